// Round 14
// baseline (271.742 us; speedup 1.0000x reference)
//
#include <hip/hip_runtime.h>

#define N_USERS 100000
#define N_ITEMS 50000
#define N_NODES (N_USERS + N_ITEMS)
#define DIM 64
#define BATCH 16384
#define RPB 512                          // rows per bucket
#define BSHIFT 9                         // log2(RPB)
#define NB ((N_NODES + RPB - 1) / RPB)   // 293 buckets
#define HP 296                           // padded hist stride
#define EPT 8                            // edges per thread in scatter
#define TILE_E (512 * EPT)               // 4096 edges per scatter block
#define STRIDE 12288                     // bcv region stride (45-sigma headroom)
#define XSCALE 64.0f                     // fp8 storage scale
#define INV_XSCALE 0.015625f             // 1/64
#define SB ((N_NODES + 15) / 16)         // 9375 spmm blocks (16 rows/block)
#define WLB ((3 * BATCH) / 16)           // 3072 worklist spmm blocks

struct __align__(8) Pair { int c; float v; };
typedef float floatx2 __attribute__((ext_vector_type(2)));

// ---- fp8 helpers (e4m3, gfx940+ builtins) ---------------------------------
__device__ __forceinline__ unsigned pk8(float a, float b, float c, float d) {
    int w = __builtin_amdgcn_cvt_pk_fp8_f32(a, b, 0, false);
    w = __builtin_amdgcn_cvt_pk_fp8_f32(c, d, w, true);
    return (unsigned)w;
}

// acc(a0..a3) += v * fp8x4(x)   — 2 cvt + 4 fma
#define EDGE_F8D(V, X) { \
    floatx2 lo_ = __builtin_amdgcn_cvt_pk_f32_fp8((X), false); \
    floatx2 hi_ = __builtin_amdgcn_cvt_pk_f32_fp8((X), true); \
    a0 = fmaf((V), lo_.x, a0); a1 = fmaf((V), lo_.y, a1); \
    a2 = fmaf((V), hi_.x, a2); a3 = fmaf((V), hi_.y, a3); }

#define LDX(P) (*(const unsigned*)(x8 + ((size_t)(P).c << 6) + q * 4))

// non-temporal Pair load (perm stream is read-once per pass)
__device__ __forceinline__ Pair ldnt(const Pair* p) {
    unsigned long long w = __builtin_nontemporal_load((const unsigned long long*)p);
    Pair r;
    r.c = (int)(unsigned)(w & 0xffffffffu);
    r.v = __uint_as_float((unsigned)(w >> 32));
    return r;
}

// ---------------------------------------------------------------------------
__device__ __forceinline__ float block_reduce_sum(float v) {
    for (int s = 32; s > 0; s >>= 1) v += __shfl_xor(v, s, 64);
    __shared__ float sm[8];
    int lane = threadIdx.x & 63;
    int wid  = threadIdx.x >> 6;
    if (lane == 0) sm[wid] = v;
    __syncthreads();
    float t = 0.0f;
    if (threadIdx.x == 0) {
        int nw = (blockDim.x + 63) >> 6;
        for (int w = 0; w < nw; ++w) t += sm[w];
    }
    return t;
}

// ---------------------------------------------------------------------------
// Convert concat [uw;iw] f32 -> fp8 (x64 scale). Also clears flags, bcursor,
// sums, and the wl/ticket control words.
// ---------------------------------------------------------------------------
__global__ void convert_kernel(const float* __restrict__ uw, const float* __restrict__ iw,
                               unsigned char* __restrict__ x8,
                               int* __restrict__ flags, int* __restrict__ bcursor,
                               float* __restrict__ sums, int* __restrict__ ctrl) {
    size_t tid = (size_t)blockIdx.x * 256 + threadIdx.x;
    if (tid == 0) { sums[0] = 0.0f; sums[1] = 0.0f; ctrl[0] = 0; ctrl[1] = 0; }
    if (tid < N_NODES) flags[tid] = 0;
    else if (tid < N_NODES + NB) bcursor[tid - N_NODES] = 0;
    size_t base = tid * 8;
    if (base >= (size_t)N_NODES * DIM) return;
    const float* src = (base < (size_t)N_USERS * DIM) ? uw + base
                                                      : iw + (base - (size_t)N_USERS * DIM);
    float4 a = ((const float4*)src)[0];
    float4 b = ((const float4*)src)[1];
    uint2 o;
    o.x = pk8(XSCALE * a.x, XSCALE * a.y, XSCALE * a.z, XSCALE * a.w);
    o.y = pk8(XSCALE * b.x, XSCALE * b.y, XSCALE * b.z, XSCALE * b.w);
    *(uint2*)(x8 + base) = o;
}

// ---------------------------------------------------------------------------
// Init: acc_0 = gathered layer-0 embeddings + reg_sum from ORIGINAL weights.
// DOWL: dedup batch rows into a compact worklist for the layer-3 spmm.
// ---------------------------------------------------------------------------
template<bool DOWL>
__global__ void init_kernel(const float* __restrict__ uw, const float* __restrict__ iw,
                            const int* __restrict__ users, const int* __restrict__ pos,
                            const int* __restrict__ neg,
                            float* __restrict__ uacc, float* __restrict__ pacc,
                            float* __restrict__ nacc, float* __restrict__ reg_sum,
                            int* __restrict__ flags, int* __restrict__ wl,
                            int* __restrict__ ctrl) {
    int tid = blockIdx.x * blockDim.x + threadIdx.x;
    if (DOWL && tid < 3 * BATCH) {
        int r = (tid < BATCH) ? users[tid]
              : (tid < 2 * BATCH) ? N_USERS + pos[tid - BATCH]
              : N_USERS + neg[tid - 2 * BATCH];
        if (atomicExch(&flags[r], 1) == 0) wl[atomicAdd(&ctrl[0], 1)] = r;
    }
    int i = tid >> 4;
    int q = tid & 15;
    if (i >= BATCH) return;
    size_t o = (size_t)i * DIM + q * 4;
    float4 u = *(const float4*)(uw + (size_t)users[i] * DIM + q * 4);
    float4 p = *(const float4*)(iw + (size_t)pos[i]   * DIM + q * 4);
    float4 n = *(const float4*)(iw + (size_t)neg[i]   * DIM + q * 4);
    *(float4*)(uacc + o) = u;
    *(float4*)(pacc + o) = p;
    *(float4*)(nacc + o) = n;
    float ss = u.x*u.x + u.y*u.y + u.z*u.z + u.w*u.w
             + p.x*p.x + p.y*p.y + p.z*p.z + p.w*p.w
             + n.x*n.x + n.y*n.y + n.z*n.z + n.w*n.w;
    float bt = block_reduce_sum(ss);
    if (threadIdx.x == 0) unsafeAtomicAdd(reg_sum, bt);
}

// ---------------------------------------------------------------------------
// Binned scatter into fixed-stride per-bucket regions.
// ---------------------------------------------------------------------------
__global__ void binned_scatter_kernel(const int* __restrict__ rows, const int* __restrict__ cols,
                                      const float* __restrict__ vals, int* __restrict__ bcursor,
                                      Pair* __restrict__ bcv, int nnz) {
    __shared__ int h[8][HP];
    int t = threadIdx.x, w = t >> 6;
    for (int i = t; i < 8 * HP; i += 512) ((int*)h)[i] = 0;
    __syncthreads();
    long long tile = (long long)blockIdx.x * TILE_E;
    int er[EPT], cr[EPT];
    float vr[EPT];
    #pragma unroll
    for (int j = 0; j < EPT; ++j) {
        long long e = tile + t + j * 512;
        if (e < nnz) {
            int r = rows[e];
            er[j] = r;
            cr[j] = cols[e];
            vr[j] = vals[e];
            atomicAdd(&h[w][r >> BSHIFT], 1);
        } else er[j] = -1;
    }
    __syncthreads();
    for (int b = t; b < NB; b += 512) {
        int cw[8], tot = 0;
        #pragma unroll
        for (int w2 = 0; w2 < 8; ++w2) { cw[w2] = h[w2][b]; tot += cw[w2]; }
        int base = tot ? (b * STRIDE + atomicAdd(&bcursor[b], tot)) : 0;
        #pragma unroll
        for (int w2 = 0; w2 < 8; ++w2) { h[w2][b] = base; base += cw[w2]; }
    }
    __syncthreads();
    #pragma unroll
    for (int j = 0; j < EPT; ++j) {
        if (er[j] >= 0) {
            int r = er[j];
            int dst = atomicAdd(&h[w][r >> BSHIFT], 1);
            Pair p;
            p.c = cr[j] | ((r & (RPB - 1)) << 18);
            p.v = vr[j];
            bcv[dst] = p;
        }
    }
}

// ---------------------------------------------------------------------------
// Post-scan: bucket counts -> dense CSR bucket bases (NB=293 <= 512).
// ---------------------------------------------------------------------------
__global__ void post_scan_kernel(const int* __restrict__ counts, int* __restrict__ bbase,
                                 int* __restrict__ rowptr, int nnz) {
    __shared__ int sm[512];
    int t = threadIdx.x;
    int v = (t < NB) ? counts[t] : 0;
    sm[t] = v;
    __syncthreads();
    for (int off = 1; off < 512; off <<= 1) {
        int tmp = (t >= off) ? sm[t - off] : 0;
        __syncthreads();
        sm[t] += tmp;
        __syncthreads();
    }
    if (t < NB) bbase[t] = sm[t] - v;
    if (t == 511) bbase[NB] = sm[511];
    if (t == 0) rowptr[N_NODES] = nnz;
}

// ---------------------------------------------------------------------------
// Per-bucket counting sort in LDS -> final dense CSR perm + rowptr.
// ---------------------------------------------------------------------------
__global__ void bucket_sort_kernel(const Pair* __restrict__ bcv,
                                   const int* __restrict__ counts,
                                   const int* __restrict__ bbase,
                                   int* __restrict__ rowptr, Pair* __restrict__ perm) {
    __shared__ int rh8[8][RPB + 8];
    __shared__ int rh[RPB];
    __shared__ int sc[RPB];
    int blk = blockIdx.x;
    int t = threadIdx.x;        // 512 threads
    int w = t >> 6;
    size_t src = (size_t)blk * STRIDE;
    int base = bbase[blk];
    int cnt  = counts[blk];
    for (int i = t; i < 8 * (RPB + 8); i += 512) ((int*)rh8)[i] = 0;
    __syncthreads();
    for (int i = t; i < cnt; i += 512)
        atomicAdd(&rh8[w][(unsigned)bcv[src + i].c >> 18], 1);
    __syncthreads();
    int v = 0;
    #pragma unroll
    for (int w2 = 0; w2 < 8; ++w2) v += rh8[w2][t];
    sc[t] = v;
    __syncthreads();
    for (int off = 1; off < 512; off <<= 1) {
        int tmp = (t >= off) ? sc[t - off] : 0;
        __syncthreads();
        sc[t] += tmp;
        __syncthreads();
    }
    int excl = sc[t] - v;
    int g = blk * RPB + t;
    if (g < N_NODES) rowptr[g] = base + excl;
    rh[t] = excl;
    __syncthreads();
    for (int i = t; i < cnt; i += 512) {
        Pair p = bcv[src + i];
        int r = (unsigned)p.c >> 18;
        int rk = atomicAdd(&rh[r], 1);
        p.c &= 0x3FFFF;
        perm[base + rk] = p;
    }
}

// ---------------------------------------------------------------------------
// SpMM per-row body (16 lanes per row; lane owns one dword = 4 dims).
// Explicit 2-stage software pipeline: issue current group's 8 x-gathers,
// then the NEXT group's 8 perm loads, then the FMAs. Named registers only.
// ---------------------------------------------------------------------------
__device__ __forceinline__ void spmm_row_f8(const unsigned char* __restrict__ x8,
                                            const Pair* __restrict__ pe,
                                            int e, int end, int q, int row,
                                            unsigned char* __restrict__ out8) {
    float a0 = 0.f, a1 = 0.f, a2 = 0.f, a3 = 0.f;
    if (e + 8 <= end) {
        Pair c0 = ldnt(pe+e),   c1 = ldnt(pe+e+1), c2 = ldnt(pe+e+2), c3 = ldnt(pe+e+3),
             c4 = ldnt(pe+e+4), c5 = ldnt(pe+e+5), c6 = ldnt(pe+e+6), c7 = ldnt(pe+e+7);
        e += 8;
        for (; e + 8 <= end; e += 8) {
            unsigned x0 = LDX(c0), x1 = LDX(c1), x2 = LDX(c2), x3 = LDX(c3),
                     x4 = LDX(c4), x5 = LDX(c5), x6 = LDX(c6), x7 = LDX(c7);
            Pair n0 = ldnt(pe+e),   n1 = ldnt(pe+e+1), n2 = ldnt(pe+e+2), n3 = ldnt(pe+e+3),
                 n4 = ldnt(pe+e+4), n5 = ldnt(pe+e+5), n6 = ldnt(pe+e+6), n7 = ldnt(pe+e+7);
            EDGE_F8D(c0.v, x0); EDGE_F8D(c1.v, x1);
            EDGE_F8D(c2.v, x2); EDGE_F8D(c3.v, x3);
            EDGE_F8D(c4.v, x4); EDGE_F8D(c5.v, x5);
            EDGE_F8D(c6.v, x6); EDGE_F8D(c7.v, x7);
            c0 = n0; c1 = n1; c2 = n2; c3 = n3;
            c4 = n4; c5 = n5; c6 = n6; c7 = n7;
        }
        unsigned x0 = LDX(c0), x1 = LDX(c1), x2 = LDX(c2), x3 = LDX(c3),
                 x4 = LDX(c4), x5 = LDX(c5), x6 = LDX(c6), x7 = LDX(c7);
        EDGE_F8D(c0.v, x0); EDGE_F8D(c1.v, x1);
        EDGE_F8D(c2.v, x2); EDGE_F8D(c3.v, x3);
        EDGE_F8D(c4.v, x4); EDGE_F8D(c5.v, x5);
        EDGE_F8D(c6.v, x6); EDGE_F8D(c7.v, x7);
    }
    for (; e < end; ++e) {
        Pair p = ldnt(pe + e);
        unsigned x = LDX(p);
        EDGE_F8D(p.v, x);
    }
    *(unsigned*)(out8 + ((size_t)row << 6) + q * 4) = pk8(a0, a1, a2, a3);
}

// ---------------------------------------------------------------------------
// Gather-accumulate body (batch rows, fp8 unscale into f32 accumulators).
// ---------------------------------------------------------------------------
__device__ __forceinline__ void gather_add_body(int tid, const unsigned char* __restrict__ x8,
                                                const int* __restrict__ users,
                                                const int* __restrict__ pos,
                                                const int* __restrict__ neg,
                                                float* __restrict__ uacc,
                                                float* __restrict__ pacc,
                                                float* __restrict__ nacc) {
    int i = tid >> 4;
    int q = tid & 15;
    if (i >= BATCH) return;
    size_t o = (size_t)i * DIM + q * 4;
    float4 a;
    unsigned u;
    floatx2 lo, hi;

    a = *(float4*)(uacc + o);
    u = *(const unsigned*)(x8 + ((size_t)users[i] << 6) + q * 4);
    lo = __builtin_amdgcn_cvt_pk_f32_fp8(u, false);
    hi = __builtin_amdgcn_cvt_pk_f32_fp8(u, true);
    a.x = fmaf(lo.x, INV_XSCALE, a.x); a.y = fmaf(lo.y, INV_XSCALE, a.y);
    a.z = fmaf(hi.x, INV_XSCALE, a.z); a.w = fmaf(hi.y, INV_XSCALE, a.w);
    *(float4*)(uacc + o) = a;

    a = *(float4*)(pacc + o);
    u = *(const unsigned*)(x8 + ((size_t)(N_USERS + pos[i]) << 6) + q * 4);
    lo = __builtin_amdgcn_cvt_pk_f32_fp8(u, false);
    hi = __builtin_amdgcn_cvt_pk_f32_fp8(u, true);
    a.x = fmaf(lo.x, INV_XSCALE, a.x); a.y = fmaf(lo.y, INV_XSCALE, a.y);
    a.z = fmaf(hi.x, INV_XSCALE, a.z); a.w = fmaf(hi.y, INV_XSCALE, a.w);
    *(float4*)(pacc + o) = a;

    a = *(float4*)(nacc + o);
    u = *(const unsigned*)(x8 + ((size_t)(N_USERS + neg[i]) << 6) + q * 4);
    lo = __builtin_amdgcn_cvt_pk_f32_fp8(u, false);
    hi = __builtin_amdgcn_cvt_pk_f32_fp8(u, true);
    a.x = fmaf(lo.x, INV_XSCALE, a.x); a.y = fmaf(lo.y, INV_XSCALE, a.y);
    a.z = fmaf(hi.x, INV_XSCALE, a.z); a.w = fmaf(hi.y, INV_XSCALE, a.w);
    *(float4*)(nacc + o) = a;
}

// ---------------------------------------------------------------------------
// Full spmm (all rows).
// ---------------------------------------------------------------------------
__global__ void spmm_f8_kernel(const unsigned char* __restrict__ x8,
                               const Pair* __restrict__ pe,
                               const int* __restrict__ rowptr,
                               unsigned char* __restrict__ out8) {
    int row = blockIdx.x * 16 + (threadIdx.x >> 4);
    if (row >= N_NODES) return;
    spmm_row_f8(x8, pe, rowptr[row], rowptr[row + 1], threadIdx.x & 15, row, out8);
}

// ---------------------------------------------------------------------------
// Fused: full spmm (blocks < SB) + previous layer's gather_add (rest).
// gather reads xsrc, which was written by the PREVIOUS dispatch — safe.
// ---------------------------------------------------------------------------
__global__ void spmm_gather_f8_kernel(const unsigned char* __restrict__ xsrc,
                                      const Pair* __restrict__ pe,
                                      const int* __restrict__ rowptr,
                                      unsigned char* __restrict__ out8,
                                      const int* __restrict__ users, const int* __restrict__ pos,
                                      const int* __restrict__ neg,
                                      float* __restrict__ uacc, float* __restrict__ pacc,
                                      float* __restrict__ nacc) {
    if (blockIdx.x < SB) {
        int row = blockIdx.x * 16 + (threadIdx.x >> 4);
        if (row >= N_NODES) return;
        spmm_row_f8(xsrc, pe, rowptr[row], rowptr[row + 1], threadIdx.x & 15, row, out8);
    } else {
        gather_add_body((blockIdx.x - SB) * 256 + threadIdx.x, xsrc,
                        users, pos, neg, uacc, pacc, nacc);
    }
}

// ---------------------------------------------------------------------------
// Fused: worklist spmm (only rows consumed by the final gather) + gather_add.
// ---------------------------------------------------------------------------
__global__ void spmm_wl_gather_f8_kernel(const unsigned char* __restrict__ xsrc,
                                         const Pair* __restrict__ pe,
                                         const int* __restrict__ rowptr,
                                         unsigned char* __restrict__ out8,
                                         const int* __restrict__ wl,
                                         const int* __restrict__ ctrl,
                                         const int* __restrict__ users, const int* __restrict__ pos,
                                         const int* __restrict__ neg,
                                         float* __restrict__ uacc, float* __restrict__ pacc,
                                         float* __restrict__ nacc) {
    if (blockIdx.x < WLB) {
        int idx = blockIdx.x * 16 + (threadIdx.x >> 4);
        if (idx >= ctrl[0]) return;
        int row = wl[idx];
        spmm_row_f8(xsrc, pe, rowptr[row], rowptr[row + 1], threadIdx.x & 15, row, out8);
    } else {
        gather_add_body((blockIdx.x - WLB) * 256 + threadIdx.x, xsrc,
                        users, pos, neg, uacc, pacc, nacc);
    }
}

// ---------------------------------------------------------------------------
// Legacy COO atomic SpMM (fallback).
// ---------------------------------------------------------------------------
__global__ void spmm_atomic_kernel(const float* __restrict__ xu, const float* __restrict__ xi,
                                   const float* __restrict__ vals, const int* __restrict__ rows,
                                   const int* __restrict__ cols,
                                   float* __restrict__ out, int nnz) {
    long long tid = (long long)blockIdx.x * blockDim.x + threadIdx.x;
    int e = (int)(tid >> 4);
    if (e >= nnz) return;
    int q = (int)(tid & 15);
    int r = rows[e];
    int c = cols[e];
    float v = vals[e];
    const float* src = (c < N_USERS) ? (xu + (size_t)c * DIM)
                                     : (xi + (size_t)(c - N_USERS) * DIM);
    float4 x = *(const float4*)(src + q * 4);
    float* dst = out + (size_t)r * DIM + q * 4;
    unsafeAtomicAdd(dst + 0, v * x.x);
    unsafeAtomicAdd(dst + 1, v * x.y);
    unsafeAtomicAdd(dst + 2, v * x.z);
    unsafeAtomicAdd(dst + 3, v * x.w);
}

// ---------------------------------------------------------------------------
// Fused layer-3 gather + BPR score + last-block finalize.
// final = acc/4, so dot scales by 1/16.
// ---------------------------------------------------------------------------
__global__ void gather_score_kernel(const unsigned char* __restrict__ x8,
                                    const int* __restrict__ users, const int* __restrict__ pos,
                                    const int* __restrict__ neg,
                                    const float* __restrict__ uacc, const float* __restrict__ pacc,
                                    const float* __restrict__ nacc, float* __restrict__ sums,
                                    int* __restrict__ ctrl, float* __restrict__ out) {
    int tid = blockIdx.x * blockDim.x + threadIdx.x;
    int i = tid >> 4;
    int q = tid & 15;
    float ps = 0.0f, ns = 0.0f;
    if (i < BATCH) {
        size_t o = (size_t)i * DIM + q * 4;
        float4 u = *(const float4*)(uacc + o);
        float4 p = *(const float4*)(pacc + o);
        float4 n = *(const float4*)(nacc + o);
        unsigned t;
        floatx2 lo, hi;
        t = *(const unsigned*)(x8 + ((size_t)users[i] << 6) + q * 4);
        lo = __builtin_amdgcn_cvt_pk_f32_fp8(t, false);
        hi = __builtin_amdgcn_cvt_pk_f32_fp8(t, true);
        u.x = fmaf(lo.x, INV_XSCALE, u.x); u.y = fmaf(lo.y, INV_XSCALE, u.y);
        u.z = fmaf(hi.x, INV_XSCALE, u.z); u.w = fmaf(hi.y, INV_XSCALE, u.w);
        t = *(const unsigned*)(x8 + ((size_t)(N_USERS + pos[i]) << 6) + q * 4);
        lo = __builtin_amdgcn_cvt_pk_f32_fp8(t, false);
        hi = __builtin_amdgcn_cvt_pk_f32_fp8(t, true);
        p.x = fmaf(lo.x, INV_XSCALE, p.x); p.y = fmaf(lo.y, INV_XSCALE, p.y);
        p.z = fmaf(hi.x, INV_XSCALE, p.z); p.w = fmaf(hi.y, INV_XSCALE, p.w);
        t = *(const unsigned*)(x8 + ((size_t)(N_USERS + neg[i]) << 6) + q * 4);
        lo = __builtin_amdgcn_cvt_pk_f32_fp8(t, false);
        hi = __builtin_amdgcn_cvt_pk_f32_fp8(t, true);
        n.x = fmaf(lo.x, INV_XSCALE, n.x); n.y = fmaf(lo.y, INV_XSCALE, n.y);
        n.z = fmaf(hi.x, INV_XSCALE, n.z); n.w = fmaf(hi.y, INV_XSCALE, n.w);
        ps = u.x*p.x + u.y*p.y + u.z*p.z + u.w*p.w;
        ns = u.x*n.x + u.y*n.y + u.z*n.z + u.w*n.w;
    }
    for (int s = 8; s > 0; s >>= 1) {
        ps += __shfl_xor(ps, s, 16);
        ns += __shfl_xor(ns, s, 16);
    }
    float term = 0.0f;
    if (q == 0 && i < BATCH) {
        float d = (ps - ns) * (1.0f / 16.0f);
        float sig = 1.0f / (1.0f + expf(-d));
        term = logf(sig + 1e-8f);
    }
    float bt = block_reduce_sum(term);
    if (threadIdx.x == 0) {
        unsafeAtomicAdd(&sums[0], bt);
        __threadfence();
        int tk = atomicAdd(&ctrl[1], 1);
        if (tk == (int)gridDim.x - 1) {
            float ls = unsafeAtomicAdd(&sums[0], 0.0f);   // coherent read
            float rs = unsafeAtomicAdd(&sums[1], 0.0f);
            out[0] = -ls / (float)BATCH;
            out[1] =  rs / (float)BATCH;
        }
    }
}

// f32 gather-add + score + finalize (fallback path)
__global__ void gather_add_kernel(const float* __restrict__ x,
                                  const int* __restrict__ users, const int* __restrict__ pos,
                                  const int* __restrict__ neg,
                                  float* __restrict__ uacc, float* __restrict__ pacc,
                                  float* __restrict__ nacc) {
    int tid = blockIdx.x * blockDim.x + threadIdx.x;
    int i = tid >> 4;
    int q = tid & 15;
    if (i >= BATCH) return;
    size_t o = (size_t)i * DIM + q * 4;
    float4 a, b;
    a = *(float4*)(uacc + o);
    b = *(const float4*)(x + (size_t)users[i] * DIM + q * 4);
    a.x += b.x; a.y += b.y; a.z += b.z; a.w += b.w;
    *(float4*)(uacc + o) = a;
    a = *(float4*)(pacc + o);
    b = *(const float4*)(x + (size_t)(N_USERS + pos[i]) * DIM + q * 4);
    a.x += b.x; a.y += b.y; a.z += b.z; a.w += b.w;
    *(float4*)(pacc + o) = a;
    a = *(float4*)(nacc + o);
    b = *(const float4*)(x + (size_t)(N_USERS + neg[i]) * DIM + q * 4);
    a.x += b.x; a.y += b.y; a.z += b.z; a.w += b.w;
    *(float4*)(nacc + o) = a;
}

__global__ void score_kernel(const float* __restrict__ uacc, const float* __restrict__ pacc,
                             const float* __restrict__ nacc, float* __restrict__ loss_sum) {
    int tid = blockIdx.x * blockDim.x + threadIdx.x;
    int i = tid >> 4;
    int q = tid & 15;
    float ps = 0.0f, ns = 0.0f;
    if (i < BATCH) {
        size_t o = (size_t)i * DIM + q * 4;
        float4 u = *(const float4*)(uacc + o);
        float4 p = *(const float4*)(pacc + o);
        float4 n = *(const float4*)(nacc + o);
        ps = u.x*p.x + u.y*p.y + u.z*p.z + u.w*p.w;
        ns = u.x*n.x + u.y*n.y + u.z*n.z + u.w*n.w;
    }
    for (int s = 8; s > 0; s >>= 1) {
        ps += __shfl_xor(ps, s, 16);
        ns += __shfl_xor(ns, s, 16);
    }
    float term = 0.0f;
    if (q == 0 && i < BATCH) {
        float d = (ps - ns) * (1.0f / 16.0f);
        float sig = 1.0f / (1.0f + expf(-d));
        term = logf(sig + 1e-8f);
    }
    float bt = block_reduce_sum(term);
    if (threadIdx.x == 0) unsafeAtomicAdd(loss_sum, bt);
}

__global__ void finalize_kernel(const float* __restrict__ sums, float* __restrict__ out) {
    if (threadIdx.x == 0 && blockIdx.x == 0) {
        out[0] = -sums[0] / (float)BATCH;
        out[1] =  sums[1] / (float)BATCH;
    }
}

static inline size_t align256(size_t x) { return (x + 255) & ~(size_t)255; }

extern "C" void kernel_launch(void* const* d_in, const int* in_sizes, int n_in,
                              void* d_out, int out_size, void* d_ws, size_t ws_size,
                              hipStream_t stream) {
    const float* uw   = (const float*)d_in[0];
    const float* iw   = (const float*)d_in[1];
    const float* vals = (const float*)d_in[2];
    const int*   rows = (const int*)d_in[3];
    const int*   cols = (const int*)d_in[4];
    const int*   users = (const int*)d_in[5];
    const int*   pos   = (const int*)d_in[6];
    const int*   neg   = (const int*)d_in[7];
    const int nnz = in_sizes[2];

    char* ws = (char*)d_ws;
    const size_t nodeBytes = (size_t)N_NODES * DIM * sizeof(float);   // 38.4 MB
    const size_t qBytes    = (size_t)N_NODES * DIM;                   // 9.6 MB (fp8)
    const size_t accBytes  = (size_t)BATCH * DIM * sizeof(float);

    size_t off = 0;
    char*  nodeReg = ws + off;            off += align256(2 * nodeBytes);   // 76.8 MB region
    float* uacc = (float*)(ws + off);     off += align256(accBytes);
    float* pacc = (float*)(ws + off);     off += align256(accBytes);
    float* nacc = (float*)(ws + off);     off += align256(accBytes);
    float* sums = (float*)(ws + off);     off += 256;   // [0]=loss, [1]=reg
    int*   ctrl = (int*)(ws + off);       off += 256;   // [0]=wl_cnt, [1]=ticket
    Pair*  perm = (Pair*)(ws + off);      off += align256((size_t)nnz * sizeof(Pair));
    int*   rowptr = (int*)(ws + off);     off += align256((size_t)(N_NODES + 1) * sizeof(int));
    int*   bbase  = (int*)(ws + off);     off += align256((size_t)(NB + 1) * sizeof(int));
    int*   bcursor= (int*)(ws + off);     off += align256((size_t)NB * sizeof(int));
    int*   flags  = (int*)(ws + off);     off += align256((size_t)N_NODES * sizeof(int));
    int*   wl     = (int*)(ws + off);     off += align256((size_t)(3 * BATCH) * sizeof(int));
    const bool fits_alias = (2 * align256(qBytes) + (size_t)NB * STRIDE * sizeof(Pair)) <= 2 * nodeBytes;
    const bool use_csr = (off <= ws_size) && fits_alias && (N_NODES < (1 << 18));

    unsigned char* xb0 = (unsigned char*)nodeReg;
    unsigned char* xb1 = (unsigned char*)(nodeReg + align256(qBytes));
    unsigned char* xb2 = (unsigned char*)(nodeReg + 2 * align256(qBytes));
    Pair*          bcv = (Pair*)(nodeReg + 2 * align256(qBytes));
    float* xA = (float*)nodeReg;
    float* xB = (float*)(nodeReg + nodeBytes);

    float* out = (float*)d_out;

    const int bthreads = BATCH * 16;
    const int bblocks  = bthreads / 256;          // 1024
    const int tblocks  = (nnz + TILE_E - 1) / TILE_E;
    const int cblocks  = (int)(((size_t)N_NODES * DIM / 8 + 255) / 256);

    if (use_csr) {
        convert_kernel<<<cblocks, 256, 0, stream>>>(uw, iw, xb0, flags, bcursor, sums, ctrl);
        init_kernel<true><<<bblocks, 256, 0, stream>>>(uw, iw, users, pos, neg,
                                                       uacc, pacc, nacc, sums + 1, flags, wl, ctrl);
        binned_scatter_kernel<<<tblocks, 512, 0, stream>>>(rows, cols, vals, bcursor, bcv, nnz);
        post_scan_kernel<<<1, 512, 0, stream>>>(bcursor, bbase, rowptr, nnz);
        bucket_sort_kernel<<<NB, 512, 0, stream>>>(bcv, bcursor, bbase, rowptr, perm);

        // Layer 1: xb0 -> xb1
        spmm_f8_kernel<<<SB, 256, 0, stream>>>(xb0, perm, rowptr, xb1);
        // Layer 2 (xb1 -> xb2) fused with gather_add of layer-1 output (xb1)
        spmm_gather_f8_kernel<<<SB + bblocks, 256, 0, stream>>>(xb1, perm, rowptr, xb2,
                                                                users, pos, neg, uacc, pacc, nacc);
        // Layer 3 (xb2 -> xb0, worklist rows only) fused with gather_add of xb2
        spmm_wl_gather_f8_kernel<<<WLB + bblocks, 256, 0, stream>>>(xb2, perm, rowptr, xb0,
                                                                    wl, ctrl, users, pos, neg,
                                                                    uacc, pacc, nacc);
        // Final gather + score + last-block finalize
        gather_score_kernel<<<bblocks, 256, 0, stream>>>(xb0, users, pos, neg,
                                                         uacc, pacc, nacc, sums, ctrl, out);
    } else {
        const long long sthreads = (long long)nnz * 16;
        const int sblocks = (int)((sthreads + 255) / 256);
        (void)hipMemsetAsync(sums, 0, 2 * sizeof(float), stream);
        (void)hipMemsetAsync(ctrl, 0, 2 * sizeof(int), stream);
        init_kernel<false><<<bblocks, 256, 0, stream>>>(uw, iw, users, pos, neg,
                                                        uacc, pacc, nacc, sums + 1, flags, wl, ctrl);
        (void)hipMemsetAsync(xA, 0, nodeBytes, stream);
        spmm_atomic_kernel<<<sblocks, 256, 0, stream>>>(uw, iw, vals, rows, cols, xA, nnz);
        gather_add_kernel<<<bblocks, 256, 0, stream>>>(xA, users, pos, neg, uacc, pacc, nacc);
        (void)hipMemsetAsync(xB, 0, nodeBytes, stream);
        spmm_atomic_kernel<<<sblocks, 256, 0, stream>>>(xA, xA + (size_t)N_USERS * DIM, vals, rows, cols, xB, nnz);
        gather_add_kernel<<<bblocks, 256, 0, stream>>>(xB, users, pos, neg, uacc, pacc, nacc);
        (void)hipMemsetAsync(xA, 0, nodeBytes, stream);
        spmm_atomic_kernel<<<sblocks, 256, 0, stream>>>(xB, xB + (size_t)N_USERS * DIM, vals, rows, cols, xA, nnz);
        gather_add_kernel<<<bblocks, 256, 0, stream>>>(xA, users, pos, neg, uacc, pacc, nacc);
        score_kernel<<<bblocks, 256, 0, stream>>>(uacc, pacc, nacc, sums);
        finalize_kernel<<<1, 1, 0, stream>>>(sums, out);
    }
}

// Round 15
// 234.751 us; speedup vs baseline: 1.1576x; 1.1576x over previous
//
#include <hip/hip_runtime.h>

#define N_USERS 100000
#define N_ITEMS 50000
#define N_NODES (N_USERS + N_ITEMS)
#define DIM 64
#define BATCH 16384
#define RPB 512                          // rows per bucket
#define BSHIFT 9                         // log2(RPB)
#define NB ((N_NODES + RPB - 1) / RPB)   // 293 buckets
#define HP 296                           // padded hist stride
#define EPT 8                            // edges per thread in scatter
#define TILE_E (512 * EPT)               // 4096 edges per scatter block
#define STRIDE 12288                     // bcv region stride (45-sigma headroom)
#define XSCALE 64.0f                     // fp8 storage scale
#define INV_XSCALE 0.015625f             // 1/64
#define SB ((N_NODES + 15) / 16)         // 9375 spmm blocks (16 rows/block)
#define WLB ((3 * BATCH) / 16)           // 3072 worklist spmm blocks

struct __align__(8) Pair { int c; float v; };
typedef float floatx2 __attribute__((ext_vector_type(2)));

// ---- fp8 helpers (e4m3, gfx940+ builtins) ---------------------------------
__device__ __forceinline__ unsigned pk8(float a, float b, float c, float d) {
    int w = __builtin_amdgcn_cvt_pk_fp8_f32(a, b, 0, false);
    w = __builtin_amdgcn_cvt_pk_fp8_f32(c, d, w, true);
    return (unsigned)w;
}

// acc(a0..a3) += v * fp8x4(x)   — 2 cvt + 4 fma
#define EDGE_F8D(V, X) { \
    floatx2 lo_ = __builtin_amdgcn_cvt_pk_f32_fp8((X), false); \
    floatx2 hi_ = __builtin_amdgcn_cvt_pk_f32_fp8((X), true); \
    a0 = fmaf((V), lo_.x, a0); a1 = fmaf((V), lo_.y, a1); \
    a2 = fmaf((V), hi_.x, a2); a3 = fmaf((V), hi_.y, a3); }

// ---------------------------------------------------------------------------
__device__ __forceinline__ float block_reduce_sum(float v) {
    for (int s = 32; s > 0; s >>= 1) v += __shfl_xor(v, s, 64);
    __shared__ float sm[8];
    int lane = threadIdx.x & 63;
    int wid  = threadIdx.x >> 6;
    if (lane == 0) sm[wid] = v;
    __syncthreads();
    float t = 0.0f;
    if (threadIdx.x == 0) {
        int nw = (blockDim.x + 63) >> 6;
        for (int w = 0; w < nw; ++w) t += sm[w];
    }
    return t;
}

// ---------------------------------------------------------------------------
// Convert concat [uw;iw] f32 -> fp8 (x64 scale). Also clears flags, bcursor,
// sums, and the wl/ticket control words.
// ---------------------------------------------------------------------------
__global__ void convert_kernel(const float* __restrict__ uw, const float* __restrict__ iw,
                               unsigned char* __restrict__ x8,
                               int* __restrict__ flags, int* __restrict__ bcursor,
                               float* __restrict__ sums, int* __restrict__ ctrl) {
    size_t tid = (size_t)blockIdx.x * 256 + threadIdx.x;
    if (tid == 0) { sums[0] = 0.0f; sums[1] = 0.0f; ctrl[0] = 0; ctrl[1] = 0; }
    if (tid < N_NODES) flags[tid] = 0;
    else if (tid < N_NODES + NB) bcursor[tid - N_NODES] = 0;
    size_t base = tid * 8;
    if (base >= (size_t)N_NODES * DIM) return;
    const float* src = (base < (size_t)N_USERS * DIM) ? uw + base
                                                      : iw + (base - (size_t)N_USERS * DIM);
    float4 a = ((const float4*)src)[0];
    float4 b = ((const float4*)src)[1];
    uint2 o;
    o.x = pk8(XSCALE * a.x, XSCALE * a.y, XSCALE * a.z, XSCALE * a.w);
    o.y = pk8(XSCALE * b.x, XSCALE * b.y, XSCALE * b.z, XSCALE * b.w);
    *(uint2*)(x8 + base) = o;
}

// ---------------------------------------------------------------------------
// Init: acc_0 = gathered layer-0 embeddings + reg_sum from ORIGINAL weights.
// DOWL: dedup batch rows into a compact worklist for the layer-3 spmm.
// ---------------------------------------------------------------------------
template<bool DOWL>
__global__ void init_kernel(const float* __restrict__ uw, const float* __restrict__ iw,
                            const int* __restrict__ users, const int* __restrict__ pos,
                            const int* __restrict__ neg,
                            float* __restrict__ uacc, float* __restrict__ pacc,
                            float* __restrict__ nacc, float* __restrict__ reg_sum,
                            int* __restrict__ flags, int* __restrict__ wl,
                            int* __restrict__ ctrl) {
    int tid = blockIdx.x * blockDim.x + threadIdx.x;
    if (DOWL && tid < 3 * BATCH) {
        int r = (tid < BATCH) ? users[tid]
              : (tid < 2 * BATCH) ? N_USERS + pos[tid - BATCH]
              : N_USERS + neg[tid - 2 * BATCH];
        if (atomicExch(&flags[r], 1) == 0) wl[atomicAdd(&ctrl[0], 1)] = r;
    }
    int i = tid >> 4;
    int q = tid & 15;
    if (i >= BATCH) return;
    size_t o = (size_t)i * DIM + q * 4;
    float4 u = *(const float4*)(uw + (size_t)users[i] * DIM + q * 4);
    float4 p = *(const float4*)(iw + (size_t)pos[i]   * DIM + q * 4);
    float4 n = *(const float4*)(iw + (size_t)neg[i]   * DIM + q * 4);
    *(float4*)(uacc + o) = u;
    *(float4*)(pacc + o) = p;
    *(float4*)(nacc + o) = n;
    float ss = u.x*u.x + u.y*u.y + u.z*u.z + u.w*u.w
             + p.x*p.x + p.y*p.y + p.z*p.z + p.w*p.w
             + n.x*n.x + n.y*n.y + n.z*n.z + n.w*n.w;
    float bt = block_reduce_sum(ss);
    if (threadIdx.x == 0) unsafeAtomicAdd(reg_sum, bt);
}

// ---------------------------------------------------------------------------
// Binned scatter into fixed-stride per-bucket regions. All global loads in
// phase 1; per-wave LDS hist; one packed 8B store per edge.
// packed c-field = col | (row_local << 18)   (col < 2^18, row_local < 512)
// ---------------------------------------------------------------------------
__global__ void binned_scatter_kernel(const int* __restrict__ rows, const int* __restrict__ cols,
                                      const float* __restrict__ vals, int* __restrict__ bcursor,
                                      Pair* __restrict__ bcv, int nnz) {
    __shared__ int h[8][HP];
    int t = threadIdx.x, w = t >> 6;
    for (int i = t; i < 8 * HP; i += 512) ((int*)h)[i] = 0;
    __syncthreads();
    long long tile = (long long)blockIdx.x * TILE_E;
    int er[EPT], cr[EPT];
    float vr[EPT];
    #pragma unroll
    for (int j = 0; j < EPT; ++j) {
        long long e = tile + t + j * 512;
        if (e < nnz) {
            int r = rows[e];
            er[j] = r;
            cr[j] = cols[e];
            vr[j] = vals[e];
            atomicAdd(&h[w][r >> BSHIFT], 1);
        } else er[j] = -1;
    }
    __syncthreads();
    for (int b = t; b < NB; b += 512) {
        int cw[8], tot = 0;
        #pragma unroll
        for (int w2 = 0; w2 < 8; ++w2) { cw[w2] = h[w2][b]; tot += cw[w2]; }
        int base = tot ? (b * STRIDE + atomicAdd(&bcursor[b], tot)) : 0;
        #pragma unroll
        for (int w2 = 0; w2 < 8; ++w2) { h[w2][b] = base; base += cw[w2]; }
    }
    __syncthreads();
    #pragma unroll
    for (int j = 0; j < EPT; ++j) {
        if (er[j] >= 0) {
            int r = er[j];
            int dst = atomicAdd(&h[w][r >> BSHIFT], 1);
            Pair p;
            p.c = cr[j] | ((r & (RPB - 1)) << 18);
            p.v = vr[j];
            bcv[dst] = p;
        }
    }
}

// ---------------------------------------------------------------------------
// Post-scan: bucket counts -> dense CSR bucket bases (NB=293 <= 512).
// ---------------------------------------------------------------------------
__global__ void post_scan_kernel(const int* __restrict__ counts, int* __restrict__ bbase,
                                 int* __restrict__ rowptr, int nnz) {
    __shared__ int sm[512];
    int t = threadIdx.x;
    int v = (t < NB) ? counts[t] : 0;
    sm[t] = v;
    __syncthreads();
    for (int off = 1; off < 512; off <<= 1) {
        int tmp = (t >= off) ? sm[t - off] : 0;
        __syncthreads();
        sm[t] += tmp;
        __syncthreads();
    }
    if (t < NB) bbase[t] = sm[t] - v;
    if (t == 511) bbase[NB] = sm[511];
    if (t == 0) rowptr[N_NODES] = nnz;
}

// ---------------------------------------------------------------------------
// Per-bucket counting sort in LDS -> final dense CSR perm + rowptr.
// ---------------------------------------------------------------------------
__global__ void bucket_sort_kernel(const Pair* __restrict__ bcv,
                                   const int* __restrict__ counts,
                                   const int* __restrict__ bbase,
                                   int* __restrict__ rowptr, Pair* __restrict__ perm) {
    __shared__ int rh8[8][RPB + 8];
    __shared__ int rh[RPB];
    __shared__ int sc[RPB];
    int blk = blockIdx.x;
    int t = threadIdx.x;        // 512 threads
    int w = t >> 6;
    size_t src = (size_t)blk * STRIDE;
    int base = bbase[blk];
    int cnt  = counts[blk];
    for (int i = t; i < 8 * (RPB + 8); i += 512) ((int*)rh8)[i] = 0;
    __syncthreads();
    for (int i = t; i < cnt; i += 512)
        atomicAdd(&rh8[w][(unsigned)bcv[src + i].c >> 18], 1);
    __syncthreads();
    int v = 0;
    #pragma unroll
    for (int w2 = 0; w2 < 8; ++w2) v += rh8[w2][t];
    sc[t] = v;
    __syncthreads();
    for (int off = 1; off < 512; off <<= 1) {
        int tmp = (t >= off) ? sc[t - off] : 0;
        __syncthreads();
        sc[t] += tmp;
        __syncthreads();
    }
    int excl = sc[t] - v;
    int g = blk * RPB + t;
    if (g < N_NODES) rowptr[g] = base + excl;
    rh[t] = excl;
    __syncthreads();
    for (int i = t; i < cnt; i += 512) {
        Pair p = bcv[src + i];
        int r = (unsigned)p.c >> 18;
        int rk = atomicAdd(&rh[r], 1);
        p.c &= 0x3FFFF;
        perm[base + rk] = p;
    }
}

// ---------------------------------------------------------------------------
// SpMM per-row body (round-11 form): 16 lanes per row (lane owns one dword =
// 4 dims); 8-deep edge unroll with PLAIN loads (compiler schedules the
// vmcnt interleave better than a hand pipeline — measured R11 vs R13/R14).
// ---------------------------------------------------------------------------
__device__ __forceinline__ void spmm_row_f8(const unsigned char* __restrict__ x8,
                                            const Pair* __restrict__ pe,
                                            int e, int end, int q, int row,
                                            unsigned char* __restrict__ out8) {
    float a0 = 0.f, a1 = 0.f, a2 = 0.f, a3 = 0.f;
    for (; e + 7 < end; e += 8) {
        Pair p0 = pe[e],     p1 = pe[e + 1], p2 = pe[e + 2], p3 = pe[e + 3];
        Pair p4 = pe[e + 4], p5 = pe[e + 5], p6 = pe[e + 6], p7 = pe[e + 7];
        unsigned x0 = *(const unsigned*)(x8 + ((size_t)p0.c << 6) + q * 4);
        unsigned x1 = *(const unsigned*)(x8 + ((size_t)p1.c << 6) + q * 4);
        unsigned x2 = *(const unsigned*)(x8 + ((size_t)p2.c << 6) + q * 4);
        unsigned x3 = *(const unsigned*)(x8 + ((size_t)p3.c << 6) + q * 4);
        unsigned x4 = *(const unsigned*)(x8 + ((size_t)p4.c << 6) + q * 4);
        unsigned x5 = *(const unsigned*)(x8 + ((size_t)p5.c << 6) + q * 4);
        unsigned x6 = *(const unsigned*)(x8 + ((size_t)p6.c << 6) + q * 4);
        unsigned x7 = *(const unsigned*)(x8 + ((size_t)p7.c << 6) + q * 4);
        EDGE_F8D(p0.v, x0); EDGE_F8D(p1.v, x1);
        EDGE_F8D(p2.v, x2); EDGE_F8D(p3.v, x3);
        EDGE_F8D(p4.v, x4); EDGE_F8D(p5.v, x5);
        EDGE_F8D(p6.v, x6); EDGE_F8D(p7.v, x7);
    }
    for (; e + 1 < end; e += 2) {
        Pair p0 = pe[e], p1 = pe[e + 1];
        unsigned x0 = *(const unsigned*)(x8 + ((size_t)p0.c << 6) + q * 4);
        unsigned x1 = *(const unsigned*)(x8 + ((size_t)p1.c << 6) + q * 4);
        EDGE_F8D(p0.v, x0); EDGE_F8D(p1.v, x1);
    }
    if (e < end) {
        Pair p = pe[e];
        unsigned x = *(const unsigned*)(x8 + ((size_t)p.c << 6) + q * 4);
        EDGE_F8D(p.v, x);
    }
    *(unsigned*)(out8 + ((size_t)row << 6) + q * 4) = pk8(a0, a1, a2, a3);
}

// Full spmm (all rows).
__global__ void spmm_f8_kernel(const unsigned char* __restrict__ x8,
                               const Pair* __restrict__ pe,
                               const int* __restrict__ rowptr,
                               unsigned char* __restrict__ out8) {
    int row = blockIdx.x * 16 + (threadIdx.x >> 4);
    if (row >= N_NODES) return;
    spmm_row_f8(x8, pe, rowptr[row], rowptr[row + 1], threadIdx.x & 15, row, out8);
}

// Worklist spmm (layer 3: only rows consumed by the final gather).
__global__ void spmm_wl_f8_kernel(const unsigned char* __restrict__ x8,
                                  const Pair* __restrict__ pe,
                                  const int* __restrict__ rowptr,
                                  const int* __restrict__ wl,
                                  const int* __restrict__ ctrl,
                                  unsigned char* __restrict__ out8) {
    int idx = blockIdx.x * 16 + (threadIdx.x >> 4);
    if (idx >= ctrl[0]) return;
    int row = wl[idx];
    spmm_row_f8(x8, pe, rowptr[row], rowptr[row + 1], threadIdx.x & 15, row, out8);
}

// ---------------------------------------------------------------------------
// Legacy COO atomic SpMM (fallback).
// ---------------------------------------------------------------------------
__global__ void spmm_atomic_kernel(const float* __restrict__ xu, const float* __restrict__ xi,
                                   const float* __restrict__ vals, const int* __restrict__ rows,
                                   const int* __restrict__ cols,
                                   float* __restrict__ out, int nnz) {
    long long tid = (long long)blockIdx.x * blockDim.x + threadIdx.x;
    int e = (int)(tid >> 4);
    if (e >= nnz) return;
    int q = (int)(tid & 15);
    int r = rows[e];
    int c = cols[e];
    float v = vals[e];
    const float* src = (c < N_USERS) ? (xu + (size_t)c * DIM)
                                     : (xi + (size_t)(c - N_USERS) * DIM);
    float4 x = *(const float4*)(src + q * 4);
    float* dst = out + (size_t)r * DIM + q * 4;
    unsafeAtomicAdd(dst + 0, v * x.x);
    unsafeAtomicAdd(dst + 1, v * x.y);
    unsafeAtomicAdd(dst + 2, v * x.z);
    unsafeAtomicAdd(dst + 3, v * x.w);
}

// ---------------------------------------------------------------------------
// Gather-accumulate a layer's fp8 output at the batch rows only (unscale).
// ---------------------------------------------------------------------------
__global__ void gather_add_f8_kernel(const unsigned char* __restrict__ x8,
                                     const int* __restrict__ users, const int* __restrict__ pos,
                                     const int* __restrict__ neg,
                                     float* __restrict__ uacc, float* __restrict__ pacc,
                                     float* __restrict__ nacc) {
    int tid = blockIdx.x * blockDim.x + threadIdx.x;
    int i = tid >> 4;
    int q = tid & 15;
    if (i >= BATCH) return;
    size_t o = (size_t)i * DIM + q * 4;
    float4 a;
    unsigned u;
    floatx2 lo, hi;

    a = *(float4*)(uacc + o);
    u = *(const unsigned*)(x8 + ((size_t)users[i] << 6) + q * 4);
    lo = __builtin_amdgcn_cvt_pk_f32_fp8(u, false);
    hi = __builtin_amdgcn_cvt_pk_f32_fp8(u, true);
    a.x = fmaf(lo.x, INV_XSCALE, a.x); a.y = fmaf(lo.y, INV_XSCALE, a.y);
    a.z = fmaf(hi.x, INV_XSCALE, a.z); a.w = fmaf(hi.y, INV_XSCALE, a.w);
    *(float4*)(uacc + o) = a;

    a = *(float4*)(pacc + o);
    u = *(const unsigned*)(x8 + ((size_t)(N_USERS + pos[i]) << 6) + q * 4);
    lo = __builtin_amdgcn_cvt_pk_f32_fp8(u, false);
    hi = __builtin_amdgcn_cvt_pk_f32_fp8(u, true);
    a.x = fmaf(lo.x, INV_XSCALE, a.x); a.y = fmaf(lo.y, INV_XSCALE, a.y);
    a.z = fmaf(hi.x, INV_XSCALE, a.z); a.w = fmaf(hi.y, INV_XSCALE, a.w);
    *(float4*)(pacc + o) = a;

    a = *(float4*)(nacc + o);
    u = *(const unsigned*)(x8 + ((size_t)(N_USERS + neg[i]) << 6) + q * 4);
    lo = __builtin_amdgcn_cvt_pk_f32_fp8(u, false);
    hi = __builtin_amdgcn_cvt_pk_f32_fp8(u, true);
    a.x = fmaf(lo.x, INV_XSCALE, a.x); a.y = fmaf(lo.y, INV_XSCALE, a.y);
    a.z = fmaf(hi.x, INV_XSCALE, a.z); a.w = fmaf(hi.y, INV_XSCALE, a.w);
    *(float4*)(nacc + o) = a;
}

// ---------------------------------------------------------------------------
// Fused layer-3 gather + BPR score + last-block finalize.
// final = acc/4, so dot scales by 1/16.
// ---------------------------------------------------------------------------
__global__ void gather_score_kernel(const unsigned char* __restrict__ x8,
                                    const int* __restrict__ users, const int* __restrict__ pos,
                                    const int* __restrict__ neg,
                                    const float* __restrict__ uacc, const float* __restrict__ pacc,
                                    const float* __restrict__ nacc, float* __restrict__ sums,
                                    int* __restrict__ ctrl, float* __restrict__ out) {
    int tid = blockIdx.x * blockDim.x + threadIdx.x;
    int i = tid >> 4;
    int q = tid & 15;
    float ps = 0.0f, ns = 0.0f;
    if (i < BATCH) {
        size_t o = (size_t)i * DIM + q * 4;
        float4 u = *(const float4*)(uacc + o);
        float4 p = *(const float4*)(pacc + o);
        float4 n = *(const float4*)(nacc + o);
        unsigned t;
        floatx2 lo, hi;
        t = *(const unsigned*)(x8 + ((size_t)users[i] << 6) + q * 4);
        lo = __builtin_amdgcn_cvt_pk_f32_fp8(t, false);
        hi = __builtin_amdgcn_cvt_pk_f32_fp8(t, true);
        u.x = fmaf(lo.x, INV_XSCALE, u.x); u.y = fmaf(lo.y, INV_XSCALE, u.y);
        u.z = fmaf(hi.x, INV_XSCALE, u.z); u.w = fmaf(hi.y, INV_XSCALE, u.w);
        t = *(const unsigned*)(x8 + ((size_t)(N_USERS + pos[i]) << 6) + q * 4);
        lo = __builtin_amdgcn_cvt_pk_f32_fp8(t, false);
        hi = __builtin_amdgcn_cvt_pk_f32_fp8(t, true);
        p.x = fmaf(lo.x, INV_XSCALE, p.x); p.y = fmaf(lo.y, INV_XSCALE, p.y);
        p.z = fmaf(hi.x, INV_XSCALE, p.z); p.w = fmaf(hi.y, INV_XSCALE, p.w);
        t = *(const unsigned*)(x8 + ((size_t)(N_USERS + neg[i]) << 6) + q * 4);
        lo = __builtin_amdgcn_cvt_pk_f32_fp8(t, false);
        hi = __builtin_amdgcn_cvt_pk_f32_fp8(t, true);
        n.x = fmaf(lo.x, INV_XSCALE, n.x); n.y = fmaf(lo.y, INV_XSCALE, n.y);
        n.z = fmaf(hi.x, INV_XSCALE, n.z); n.w = fmaf(hi.y, INV_XSCALE, n.w);
        ps = u.x*p.x + u.y*p.y + u.z*p.z + u.w*p.w;
        ns = u.x*n.x + u.y*n.y + u.z*n.z + u.w*n.w;
    }
    for (int s = 8; s > 0; s >>= 1) {
        ps += __shfl_xor(ps, s, 16);
        ns += __shfl_xor(ns, s, 16);
    }
    float term = 0.0f;
    if (q == 0 && i < BATCH) {
        float d = (ps - ns) * (1.0f / 16.0f);
        float sig = 1.0f / (1.0f + expf(-d));
        term = logf(sig + 1e-8f);
    }
    float bt = block_reduce_sum(term);
    if (threadIdx.x == 0) {
        unsafeAtomicAdd(&sums[0], bt);
        __threadfence();
        int tk = atomicAdd(&ctrl[1], 1);
        if (tk == (int)gridDim.x - 1) {
            float ls = unsafeAtomicAdd(&sums[0], 0.0f);   // coherent read
            float rs = unsafeAtomicAdd(&sums[1], 0.0f);
            out[0] = -ls / (float)BATCH;
            out[1] =  rs / (float)BATCH;
        }
    }
}

// f32 gather-add + score + finalize (fallback path)
__global__ void gather_add_kernel(const float* __restrict__ x,
                                  const int* __restrict__ users, const int* __restrict__ pos,
                                  const int* __restrict__ neg,
                                  float* __restrict__ uacc, float* __restrict__ pacc,
                                  float* __restrict__ nacc) {
    int tid = blockIdx.x * blockDim.x + threadIdx.x;
    int i = tid >> 4;
    int q = tid & 15;
    if (i >= BATCH) return;
    size_t o = (size_t)i * DIM + q * 4;
    float4 a, b;
    a = *(float4*)(uacc + o);
    b = *(const float4*)(x + (size_t)users[i] * DIM + q * 4);
    a.x += b.x; a.y += b.y; a.z += b.z; a.w += b.w;
    *(float4*)(uacc + o) = a;
    a = *(float4*)(pacc + o);
    b = *(const float4*)(x + (size_t)(N_USERS + pos[i]) * DIM + q * 4);
    a.x += b.x; a.y += b.y; a.z += b.z; a.w += b.w;
    *(float4*)(pacc + o) = a;
    a = *(float4*)(nacc + o);
    b = *(const float4*)(x + (size_t)(N_USERS + neg[i]) * DIM + q * 4);
    a.x += b.x; a.y += b.y; a.z += b.z; a.w += b.w;
    *(float4*)(nacc + o) = a;
}

__global__ void score_kernel(const float* __restrict__ uacc, const float* __restrict__ pacc,
                             const float* __restrict__ nacc, float* __restrict__ loss_sum) {
    int tid = blockIdx.x * blockDim.x + threadIdx.x;
    int i = tid >> 4;
    int q = tid & 15;
    float ps = 0.0f, ns = 0.0f;
    if (i < BATCH) {
        size_t o = (size_t)i * DIM + q * 4;
        float4 u = *(const float4*)(uacc + o);
        float4 p = *(const float4*)(pacc + o);
        float4 n = *(const float4*)(nacc + o);
        ps = u.x*p.x + u.y*p.y + u.z*p.z + u.w*p.w;
        ns = u.x*n.x + u.y*n.y + u.z*n.z + u.w*n.w;
    }
    for (int s = 8; s > 0; s >>= 1) {
        ps += __shfl_xor(ps, s, 16);
        ns += __shfl_xor(ns, s, 16);
    }
    float term = 0.0f;
    if (q == 0 && i < BATCH) {
        float d = (ps - ns) * (1.0f / 16.0f);
        float sig = 1.0f / (1.0f + expf(-d));
        term = logf(sig + 1e-8f);
    }
    float bt = block_reduce_sum(term);
    if (threadIdx.x == 0) unsafeAtomicAdd(loss_sum, bt);
}

__global__ void finalize_kernel(const float* __restrict__ sums, float* __restrict__ out) {
    if (threadIdx.x == 0 && blockIdx.x == 0) {
        out[0] = -sums[0] / (float)BATCH;
        out[1] =  sums[1] / (float)BATCH;
    }
}

static inline size_t align256(size_t x) { return (x + 255) & ~(size_t)255; }

extern "C" void kernel_launch(void* const* d_in, const int* in_sizes, int n_in,
                              void* d_out, int out_size, void* d_ws, size_t ws_size,
                              hipStream_t stream) {
    const float* uw   = (const float*)d_in[0];
    const float* iw   = (const float*)d_in[1];
    const float* vals = (const float*)d_in[2];
    const int*   rows = (const int*)d_in[3];
    const int*   cols = (const int*)d_in[4];
    const int*   users = (const int*)d_in[5];
    const int*   pos   = (const int*)d_in[6];
    const int*   neg   = (const int*)d_in[7];
    const int nnz = in_sizes[2];

    char* ws = (char*)d_ws;
    const size_t nodeBytes = (size_t)N_NODES * DIM * sizeof(float);   // 38.4 MB
    const size_t qBytes    = (size_t)N_NODES * DIM;                   // 9.6 MB (fp8)
    const size_t accBytes  = (size_t)BATCH * DIM * sizeof(float);

    size_t off = 0;
    char*  nodeReg = ws + off;            off += align256(2 * nodeBytes);   // 76.8 MB region
    float* uacc = (float*)(ws + off);     off += align256(accBytes);
    float* pacc = (float*)(ws + off);     off += align256(accBytes);
    float* nacc = (float*)(ws + off);     off += align256(accBytes);
    float* sums = (float*)(ws + off);     off += 256;   // [0]=loss, [1]=reg
    int*   ctrl = (int*)(ws + off);       off += 256;   // [0]=wl_cnt, [1]=ticket
    Pair*  perm = (Pair*)(ws + off);      off += align256((size_t)nnz * sizeof(Pair));
    int*   rowptr = (int*)(ws + off);     off += align256((size_t)(N_NODES + 1) * sizeof(int));
    int*   bbase  = (int*)(ws + off);     off += align256((size_t)(NB + 1) * sizeof(int));
    int*   bcursor= (int*)(ws + off);     off += align256((size_t)NB * sizeof(int));
    int*   flags  = (int*)(ws + off);     off += align256((size_t)N_NODES * sizeof(int));
    int*   wl     = (int*)(ws + off);     off += align256((size_t)(3 * BATCH) * sizeof(int));
    const bool fits_alias = (2 * align256(qBytes) + (size_t)NB * STRIDE * sizeof(Pair)) <= 2 * nodeBytes;
    const bool use_csr = (off <= ws_size) && fits_alias && (N_NODES < (1 << 18));

    unsigned char* xb0 = (unsigned char*)nodeReg;
    unsigned char* xb1 = (unsigned char*)(nodeReg + align256(qBytes));
    unsigned char* xb2 = (unsigned char*)(nodeReg + 2 * align256(qBytes));
    Pair*          bcv = (Pair*)(nodeReg + 2 * align256(qBytes));
    float* xA = (float*)nodeReg;
    float* xB = (float*)(nodeReg + nodeBytes);

    float* out = (float*)d_out;

    const int bthreads = BATCH * 16;
    const int bblocks  = bthreads / 256;          // 1024
    const int tblocks  = (nnz + TILE_E - 1) / TILE_E;
    const int cblocks  = (int)(((size_t)N_NODES * DIM / 8 + 255) / 256);

    if (use_csr) {
        convert_kernel<<<cblocks, 256, 0, stream>>>(uw, iw, xb0, flags, bcursor, sums, ctrl);
        init_kernel<true><<<bblocks, 256, 0, stream>>>(uw, iw, users, pos, neg,
                                                       uacc, pacc, nacc, sums + 1, flags, wl, ctrl);
        binned_scatter_kernel<<<tblocks, 512, 0, stream>>>(rows, cols, vals, bcursor, bcv, nnz);
        post_scan_kernel<<<1, 512, 0, stream>>>(bcursor, bbase, rowptr, nnz);
        bucket_sort_kernel<<<NB, 512, 0, stream>>>(bcv, bcursor, bbase, rowptr, perm);

        // Layer 1: xb0 -> xb1
        spmm_f8_kernel<<<SB, 256, 0, stream>>>(xb0, perm, rowptr, xb1);
        gather_add_f8_kernel<<<bblocks, 256, 0, stream>>>(xb1, users, pos, neg, uacc, pacc, nacc);
        // Layer 2: xb1 -> xb2 (bcv dead after sort)
        spmm_f8_kernel<<<SB, 256, 0, stream>>>(xb1, perm, rowptr, xb2);
        gather_add_f8_kernel<<<bblocks, 256, 0, stream>>>(xb2, users, pos, neg, uacc, pacc, nacc);
        // Layer 3: xb2 -> xb0, worklist rows only
        spmm_wl_f8_kernel<<<WLB, 256, 0, stream>>>(xb2, perm, rowptr, wl, ctrl, xb0);
        // Final gather + score + last-block finalize
        gather_score_kernel<<<bblocks, 256, 0, stream>>>(xb0, users, pos, neg,
                                                         uacc, pacc, nacc, sums, ctrl, out);
    } else {
        const long long sthreads = (long long)nnz * 16;
        const int sblocks = (int)((sthreads + 255) / 256);
        (void)hipMemsetAsync(sums, 0, 2 * sizeof(float), stream);
        (void)hipMemsetAsync(ctrl, 0, 2 * sizeof(int), stream);
        init_kernel<false><<<bblocks, 256, 0, stream>>>(uw, iw, users, pos, neg,
                                                        uacc, pacc, nacc, sums + 1, flags, wl, ctrl);
        (void)hipMemsetAsync(xA, 0, nodeBytes, stream);
        spmm_atomic_kernel<<<sblocks, 256, 0, stream>>>(uw, iw, vals, rows, cols, xA, nnz);
        gather_add_kernel<<<bblocks, 256, 0, stream>>>(xA, users, pos, neg, uacc, pacc, nacc);
        (void)hipMemsetAsync(xB, 0, nodeBytes, stream);
        spmm_atomic_kernel<<<sblocks, 256, 0, stream>>>(xA, xA + (size_t)N_USERS * DIM, vals, rows, cols, xB, nnz);
        gather_add_kernel<<<bblocks, 256, 0, stream>>>(xB, users, pos, neg, uacc, pacc, nacc);
        (void)hipMemsetAsync(xA, 0, nodeBytes, stream);
        spmm_atomic_kernel<<<sblocks, 256, 0, stream>>>(xB, xB + (size_t)N_USERS * DIM, vals, rows, cols, xA, nnz);
        gather_add_kernel<<<bblocks, 256, 0, stream>>>(xA, users, pos, neg, uacc, pacc, nacc);
        score_kernel<<<bblocks, 256, 0, stream>>>(uacc, pacc, nacc, sums);
        finalize_kernel<<<1, 1, 0, stream>>>(sums, out);
    }
}

// Round 16
// 231.768 us; speedup vs baseline: 1.1725x; 1.0129x over previous
//
#include <hip/hip_runtime.h>

#define N_USERS 100000
#define N_ITEMS 50000
#define N_NODES (N_USERS + N_ITEMS)
#define DIM 64
#define BATCH 16384
#define RPB 512                          // rows per bucket
#define BSHIFT 9                         // log2(RPB)
#define NB ((N_NODES + RPB - 1) / RPB)   // 293 buckets
#define HP 296                           // padded hist stride (9.4 KB LDS total)
#define EPT 4                            // edges per thread in scatter
#define TILE_E (512 * EPT)               // 2048 edges per scatter block
#define STRIDE 12288                     // bcv region stride (45-sigma headroom)
#define XSCALE 64.0f                     // fp8 storage scale
#define INV_XSCALE 0.015625f             // 1/64
#define SB ((N_NODES + 15) / 16)         // 9375 spmm blocks (16 rows/block)
#define WLB ((3 * BATCH) / 16)           // 3072 worklist spmm blocks
// fused build_kernel block partition (512 threads/block)
#define CVB (((size_t)N_NODES * DIM / 8 + 511) / 512)   // 2344 convert blocks
#define INB (BATCH * 16 / 512)                          // 512 init blocks

struct __align__(8) Pair { int c; float v; };
typedef float floatx2 __attribute__((ext_vector_type(2)));

// ---- fp8 helpers (e4m3, gfx940+ builtins) ---------------------------------
__device__ __forceinline__ unsigned pk8(float a, float b, float c, float d) {
    int w = __builtin_amdgcn_cvt_pk_fp8_f32(a, b, 0, false);
    w = __builtin_amdgcn_cvt_pk_fp8_f32(c, d, w, true);
    return (unsigned)w;
}

// acc(a0..a3) += v * fp8x4(x)   — 2 cvt + 4 fma
#define EDGE_F8D(V, X) { \
    floatx2 lo_ = __builtin_amdgcn_cvt_pk_f32_fp8((X), false); \
    floatx2 hi_ = __builtin_amdgcn_cvt_pk_f32_fp8((X), true); \
    a0 = fmaf((V), lo_.x, a0); a1 = fmaf((V), lo_.y, a1); \
    a2 = fmaf((V), hi_.x, a2); a3 = fmaf((V), hi_.y, a3); }

// ---------------------------------------------------------------------------
__device__ __forceinline__ float block_reduce_sum(float v) {
    for (int s = 32; s > 0; s >>= 1) v += __shfl_xor(v, s, 64);
    __shared__ float sm[8];
    int lane = threadIdx.x & 63;
    int wid  = threadIdx.x >> 6;
    if (lane == 0) sm[wid] = v;
    __syncthreads();
    float t = 0.0f;
    if (threadIdx.x == 0) {
        int nw = (blockDim.x + 63) >> 6;
        for (int w = 0; w < nw; ++w) t += sm[w];
    }
    return t;
}

// ---------------------------------------------------------------------------
// Fused build: blocks [0,SCB) binned scatter; [SCB,SCB+CVB) f32->fp8 convert;
// [SCB+CVB, +INB) init (acc0 gather + reg_sum + worklist dedup).
// All three are mutually independent; flags/bcursor/sums/ctrl are pre-zeroed
// by one hipMemsetAsync before this kernel.
// ---------------------------------------------------------------------------
__global__ void build_kernel(const int* __restrict__ rows, const int* __restrict__ cols,
                             const float* __restrict__ vals, int* __restrict__ bcursor,
                             Pair* __restrict__ bcv, int nnz, int scb,
                             const float* __restrict__ uw, const float* __restrict__ iw,
                             unsigned char* __restrict__ x8,
                             const int* __restrict__ users, const int* __restrict__ pos,
                             const int* __restrict__ neg,
                             float* __restrict__ uacc, float* __restrict__ pacc,
                             float* __restrict__ nacc, float* __restrict__ reg_sum,
                             int* __restrict__ flags, int* __restrict__ wl,
                             int* __restrict__ ctrl) {
    __shared__ int h[8][HP];
    int t = threadIdx.x;
    if ((int)blockIdx.x < scb) {
        // ---- binned scatter (EPT=4) ----
        int w = t >> 6;
        for (int i = t; i < 8 * HP; i += 512) ((int*)h)[i] = 0;
        __syncthreads();
        long long tile = (long long)blockIdx.x * TILE_E;
        int er[EPT], cr[EPT];
        float vr[EPT];
        #pragma unroll
        for (int j = 0; j < EPT; ++j) {
            long long e = tile + t + j * 512;
            if (e < nnz) {
                int r = rows[e];
                er[j] = r;
                cr[j] = cols[e];
                vr[j] = vals[e];
                atomicAdd(&h[w][r >> BSHIFT], 1);
            } else er[j] = -1;
        }
        __syncthreads();
        for (int b = t; b < NB; b += 512) {
            int cw[8], tot = 0;
            #pragma unroll
            for (int w2 = 0; w2 < 8; ++w2) { cw[w2] = h[w2][b]; tot += cw[w2]; }
            int base = tot ? (b * STRIDE + atomicAdd(&bcursor[b], tot)) : 0;
            #pragma unroll
            for (int w2 = 0; w2 < 8; ++w2) { h[w2][b] = base; base += cw[w2]; }
        }
        __syncthreads();
        #pragma unroll
        for (int j = 0; j < EPT; ++j) {
            if (er[j] >= 0) {
                int r = er[j];
                int dst = atomicAdd(&h[w][r >> BSHIFT], 1);
                Pair p;
                p.c = cr[j] | ((r & (RPB - 1)) << 18);
                p.v = vr[j];
                bcv[dst] = p;
            }
        }
    } else if (blockIdx.x < (unsigned)(scb + (int)CVB)) {
        // ---- convert [uw;iw] -> fp8 ----
        size_t tid = (size_t)(blockIdx.x - scb) * 512 + t;
        size_t base = tid * 8;
        if (base >= (size_t)N_NODES * DIM) return;
        const float* src = (base < (size_t)N_USERS * DIM) ? uw + base
                                                          : iw + (base - (size_t)N_USERS * DIM);
        float4 a = ((const float4*)src)[0];
        float4 b = ((const float4*)src)[1];
        uint2 o;
        o.x = pk8(XSCALE * a.x, XSCALE * a.y, XSCALE * a.z, XSCALE * a.w);
        o.y = pk8(XSCALE * b.x, XSCALE * b.y, XSCALE * b.z, XSCALE * b.w);
        *(uint2*)(x8 + base) = o;
    } else {
        // ---- init: acc0 gather + reg_sum + worklist dedup ----
        int tid = (int)(blockIdx.x - scb - (int)CVB) * 512 + t;
        if (tid < 3 * BATCH) {
            int r = (tid < BATCH) ? users[tid]
                  : (tid < 2 * BATCH) ? N_USERS + pos[tid - BATCH]
                  : N_USERS + neg[tid - 2 * BATCH];
            if (atomicExch(&flags[r], 1) == 0) wl[atomicAdd(&ctrl[0], 1)] = r;
        }
        int i = tid >> 4;
        int q = tid & 15;
        float ss = 0.0f;
        if (i < BATCH) {
            size_t o = (size_t)i * DIM + q * 4;
            float4 u = *(const float4*)(uw + (size_t)users[i] * DIM + q * 4);
            float4 p = *(const float4*)(iw + (size_t)pos[i]   * DIM + q * 4);
            float4 n = *(const float4*)(iw + (size_t)neg[i]   * DIM + q * 4);
            *(float4*)(uacc + o) = u;
            *(float4*)(pacc + o) = p;
            *(float4*)(nacc + o) = n;
            ss = u.x*u.x + u.y*u.y + u.z*u.z + u.w*u.w
               + p.x*p.x + p.y*p.y + p.z*p.z + p.w*p.w
               + n.x*n.x + n.y*n.y + n.z*n.z + n.w*n.w;
        }
        float bt = block_reduce_sum(ss);
        if (t == 0) unsafeAtomicAdd(reg_sum, bt);
    }
}

// ---------------------------------------------------------------------------
// Post-scan: bucket counts -> dense CSR bucket bases (NB=293 <= 512).
// ---------------------------------------------------------------------------
__global__ void post_scan_kernel(const int* __restrict__ counts, int* __restrict__ bbase,
                                 int* __restrict__ rowptr, int nnz) {
    __shared__ int sm[512];
    int t = threadIdx.x;
    int v = (t < NB) ? counts[t] : 0;
    sm[t] = v;
    __syncthreads();
    for (int off = 1; off < 512; off <<= 1) {
        int tmp = (t >= off) ? sm[t - off] : 0;
        __syncthreads();
        sm[t] += tmp;
        __syncthreads();
    }
    if (t < NB) bbase[t] = sm[t] - v;
    if (t == 511) bbase[NB] = sm[511];
    if (t == 0) rowptr[N_NODES] = nnz;
}

// ---------------------------------------------------------------------------
// Per-bucket counting sort in LDS -> final dense CSR perm + rowptr.
// ---------------------------------------------------------------------------
__global__ void bucket_sort_kernel(const Pair* __restrict__ bcv,
                                   const int* __restrict__ counts,
                                   const int* __restrict__ bbase,
                                   int* __restrict__ rowptr, Pair* __restrict__ perm) {
    __shared__ int rh8[8][RPB + 8];
    __shared__ int rh[RPB];
    __shared__ int sc[RPB];
    int blk = blockIdx.x;
    int t = threadIdx.x;        // 512 threads
    int w = t >> 6;
    size_t src = (size_t)blk * STRIDE;
    int base = bbase[blk];
    int cnt  = counts[blk];
    for (int i = t; i < 8 * (RPB + 8); i += 512) ((int*)rh8)[i] = 0;
    __syncthreads();
    for (int i = t; i < cnt; i += 512)
        atomicAdd(&rh8[w][(unsigned)bcv[src + i].c >> 18], 1);
    __syncthreads();
    int v = 0;
    #pragma unroll
    for (int w2 = 0; w2 < 8; ++w2) v += rh8[w2][t];
    sc[t] = v;
    __syncthreads();
    for (int off = 1; off < 512; off <<= 1) {
        int tmp = (t >= off) ? sc[t - off] : 0;
        __syncthreads();
        sc[t] += tmp;
        __syncthreads();
    }
    int excl = sc[t] - v;
    int g = blk * RPB + t;
    if (g < N_NODES) rowptr[g] = base + excl;
    rh[t] = excl;
    __syncthreads();
    for (int i = t; i < cnt; i += 512) {
        Pair p = bcv[src + i];
        int r = (unsigned)p.c >> 18;
        int rk = atomicAdd(&rh[r], 1);
        p.c &= 0x3FFFF;
        perm[base + rk] = p;
    }
}

// ---------------------------------------------------------------------------
// SpMM per-row body (round-11 form): 16 lanes per row (lane owns one dword =
// 4 dims); 8-deep edge unroll with PLAIN loads (compiler schedules the
// vmcnt interleave better than a hand pipeline — measured R11 vs R13/R14).
// ---------------------------------------------------------------------------
__device__ __forceinline__ void spmm_row_f8(const unsigned char* __restrict__ x8,
                                            const Pair* __restrict__ pe,
                                            int e, int end, int q, int row,
                                            unsigned char* __restrict__ out8) {
    float a0 = 0.f, a1 = 0.f, a2 = 0.f, a3 = 0.f;
    for (; e + 7 < end; e += 8) {
        Pair p0 = pe[e],     p1 = pe[e + 1], p2 = pe[e + 2], p3 = pe[e + 3];
        Pair p4 = pe[e + 4], p5 = pe[e + 5], p6 = pe[e + 6], p7 = pe[e + 7];
        unsigned x0 = *(const unsigned*)(x8 + ((size_t)p0.c << 6) + q * 4);
        unsigned x1 = *(const unsigned*)(x8 + ((size_t)p1.c << 6) + q * 4);
        unsigned x2 = *(const unsigned*)(x8 + ((size_t)p2.c << 6) + q * 4);
        unsigned x3 = *(const unsigned*)(x8 + ((size_t)p3.c << 6) + q * 4);
        unsigned x4 = *(const unsigned*)(x8 + ((size_t)p4.c << 6) + q * 4);
        unsigned x5 = *(const unsigned*)(x8 + ((size_t)p5.c << 6) + q * 4);
        unsigned x6 = *(const unsigned*)(x8 + ((size_t)p6.c << 6) + q * 4);
        unsigned x7 = *(const unsigned*)(x8 + ((size_t)p7.c << 6) + q * 4);
        EDGE_F8D(p0.v, x0); EDGE_F8D(p1.v, x1);
        EDGE_F8D(p2.v, x2); EDGE_F8D(p3.v, x3);
        EDGE_F8D(p4.v, x4); EDGE_F8D(p5.v, x5);
        EDGE_F8D(p6.v, x6); EDGE_F8D(p7.v, x7);
    }
    for (; e + 1 < end; e += 2) {
        Pair p0 = pe[e], p1 = pe[e + 1];
        unsigned x0 = *(const unsigned*)(x8 + ((size_t)p0.c << 6) + q * 4);
        unsigned x1 = *(const unsigned*)(x8 + ((size_t)p1.c << 6) + q * 4);
        EDGE_F8D(p0.v, x0); EDGE_F8D(p1.v, x1);
    }
    if (e < end) {
        Pair p = pe[e];
        unsigned x = *(const unsigned*)(x8 + ((size_t)p.c << 6) + q * 4);
        EDGE_F8D(p.v, x);
    }
    *(unsigned*)(out8 + ((size_t)row << 6) + q * 4) = pk8(a0, a1, a2, a3);
}

// Full spmm (all rows).
__global__ void spmm_f8_kernel(const unsigned char* __restrict__ x8,
                               const Pair* __restrict__ pe,
                               const int* __restrict__ rowptr,
                               unsigned char* __restrict__ out8) {
    int row = blockIdx.x * 16 + (threadIdx.x >> 4);
    if (row >= N_NODES) return;
    spmm_row_f8(x8, pe, rowptr[row], rowptr[row + 1], threadIdx.x & 15, row, out8);
}

// Worklist spmm (layer 3: only rows consumed by the final gather).
__global__ void spmm_wl_f8_kernel(const unsigned char* __restrict__ x8,
                                  const Pair* __restrict__ pe,
                                  const int* __restrict__ rowptr,
                                  const int* __restrict__ wl,
                                  const int* __restrict__ ctrl,
                                  unsigned char* __restrict__ out8) {
    int idx = blockIdx.x * 16 + (threadIdx.x >> 4);
    if (idx >= ctrl[0]) return;
    int row = wl[idx];
    spmm_row_f8(x8, pe, rowptr[row], rowptr[row + 1], threadIdx.x & 15, row, out8);
}

// ---------------------------------------------------------------------------
// Legacy COO atomic SpMM (fallback).
// ---------------------------------------------------------------------------
__global__ void spmm_atomic_kernel(const float* __restrict__ xu, const float* __restrict__ xi,
                                   const float* __restrict__ vals, const int* __restrict__ rows,
                                   const int* __restrict__ cols,
                                   float* __restrict__ out, int nnz) {
    long long tid = (long long)blockIdx.x * blockDim.x + threadIdx.x;
    int e = (int)(tid >> 4);
    if (e >= nnz) return;
    int q = (int)(tid & 15);
    int r = rows[e];
    int c = cols[e];
    float v = vals[e];
    const float* src = (c < N_USERS) ? (xu + (size_t)c * DIM)
                                     : (xi + (size_t)(c - N_USERS) * DIM);
    float4 x = *(const float4*)(src + q * 4);
    float* dst = out + (size_t)r * DIM + q * 4;
    unsafeAtomicAdd(dst + 0, v * x.x);
    unsafeAtomicAdd(dst + 1, v * x.y);
    unsafeAtomicAdd(dst + 2, v * x.z);
    unsafeAtomicAdd(dst + 3, v * x.w);
}

// ---------------------------------------------------------------------------
// Gather-accumulate a layer's fp8 output at the batch rows only (unscale).
// ---------------------------------------------------------------------------
__global__ void gather_add_f8_kernel(const unsigned char* __restrict__ x8,
                                     const int* __restrict__ users, const int* __restrict__ pos,
                                     const int* __restrict__ neg,
                                     float* __restrict__ uacc, float* __restrict__ pacc,
                                     float* __restrict__ nacc) {
    int tid = blockIdx.x * blockDim.x + threadIdx.x;
    int i = tid >> 4;
    int q = tid & 15;
    if (i >= BATCH) return;
    size_t o = (size_t)i * DIM + q * 4;
    float4 a;
    unsigned u;
    floatx2 lo, hi;

    a = *(float4*)(uacc + o);
    u = *(const unsigned*)(x8 + ((size_t)users[i] << 6) + q * 4);
    lo = __builtin_amdgcn_cvt_pk_f32_fp8(u, false);
    hi = __builtin_amdgcn_cvt_pk_f32_fp8(u, true);
    a.x = fmaf(lo.x, INV_XSCALE, a.x); a.y = fmaf(lo.y, INV_XSCALE, a.y);
    a.z = fmaf(hi.x, INV_XSCALE, a.z); a.w = fmaf(hi.y, INV_XSCALE, a.w);
    *(float4*)(uacc + o) = a;

    a = *(float4*)(pacc + o);
    u = *(const unsigned*)(x8 + ((size_t)(N_USERS + pos[i]) << 6) + q * 4);
    lo = __builtin_amdgcn_cvt_pk_f32_fp8(u, false);
    hi = __builtin_amdgcn_cvt_pk_f32_fp8(u, true);
    a.x = fmaf(lo.x, INV_XSCALE, a.x); a.y = fmaf(lo.y, INV_XSCALE, a.y);
    a.z = fmaf(hi.x, INV_XSCALE, a.z); a.w = fmaf(hi.y, INV_XSCALE, a.w);
    *(float4*)(pacc + o) = a;

    a = *(float4*)(nacc + o);
    u = *(const unsigned*)(x8 + ((size_t)(N_USERS + neg[i]) << 6) + q * 4);
    lo = __builtin_amdgcn_cvt_pk_f32_fp8(u, false);
    hi = __builtin_amdgcn_cvt_pk_f32_fp8(u, true);
    a.x = fmaf(lo.x, INV_XSCALE, a.x); a.y = fmaf(lo.y, INV_XSCALE, a.y);
    a.z = fmaf(hi.x, INV_XSCALE, a.z); a.w = fmaf(hi.y, INV_XSCALE, a.w);
    *(float4*)(nacc + o) = a;
}

// ---------------------------------------------------------------------------
// Fused layer-3 gather + BPR score + last-block finalize.
// final = acc/4, so dot scales by 1/16.
// ---------------------------------------------------------------------------
__global__ void gather_score_kernel(const unsigned char* __restrict__ x8,
                                    const int* __restrict__ users, const int* __restrict__ pos,
                                    const int* __restrict__ neg,
                                    const float* __restrict__ uacc, const float* __restrict__ pacc,
                                    const float* __restrict__ nacc, float* __restrict__ sums,
                                    int* __restrict__ ctrl, float* __restrict__ out) {
    int tid = blockIdx.x * blockDim.x + threadIdx.x;
    int i = tid >> 4;
    int q = tid & 15;
    float ps = 0.0f, ns = 0.0f;
    if (i < BATCH) {
        size_t o = (size_t)i * DIM + q * 4;
        float4 u = *(const float4*)(uacc + o);
        float4 p = *(const float4*)(pacc + o);
        float4 n = *(const float4*)(nacc + o);
        unsigned t;
        floatx2 lo, hi;
        t = *(const unsigned*)(x8 + ((size_t)users[i] << 6) + q * 4);
        lo = __builtin_amdgcn_cvt_pk_f32_fp8(t, false);
        hi = __builtin_amdgcn_cvt_pk_f32_fp8(t, true);
        u.x = fmaf(lo.x, INV_XSCALE, u.x); u.y = fmaf(lo.y, INV_XSCALE, u.y);
        u.z = fmaf(hi.x, INV_XSCALE, u.z); u.w = fmaf(hi.y, INV_XSCALE, u.w);
        t = *(const unsigned*)(x8 + ((size_t)(N_USERS + pos[i]) << 6) + q * 4);
        lo = __builtin_amdgcn_cvt_pk_f32_fp8(t, false);
        hi = __builtin_amdgcn_cvt_pk_f32_fp8(t, true);
        p.x = fmaf(lo.x, INV_XSCALE, p.x); p.y = fmaf(lo.y, INV_XSCALE, p.y);
        p.z = fmaf(hi.x, INV_XSCALE, p.z); p.w = fmaf(hi.y, INV_XSCALE, p.w);
        t = *(const unsigned*)(x8 + ((size_t)(N_USERS + neg[i]) << 6) + q * 4);
        lo = __builtin_amdgcn_cvt_pk_f32_fp8(t, false);
        hi = __builtin_amdgcn_cvt_pk_f32_fp8(t, true);
        n.x = fmaf(lo.x, INV_XSCALE, n.x); n.y = fmaf(lo.y, INV_XSCALE, n.y);
        n.z = fmaf(hi.x, INV_XSCALE, n.z); n.w = fmaf(hi.y, INV_XSCALE, n.w);
        ps = u.x*p.x + u.y*p.y + u.z*p.z + u.w*p.w;
        ns = u.x*n.x + u.y*n.y + u.z*n.z + u.w*n.w;
    }
    for (int s = 8; s > 0; s >>= 1) {
        ps += __shfl_xor(ps, s, 16);
        ns += __shfl_xor(ns, s, 16);
    }
    float term = 0.0f;
    if (q == 0 && i < BATCH) {
        float d = (ps - ns) * (1.0f / 16.0f);
        float sig = 1.0f / (1.0f + expf(-d));
        term = logf(sig + 1e-8f);
    }
    float bt = block_reduce_sum(term);
    if (threadIdx.x == 0) {
        unsafeAtomicAdd(&sums[0], bt);
        __threadfence();
        int tk = atomicAdd(&ctrl[1], 1);
        if (tk == (int)gridDim.x - 1) {
            float ls = unsafeAtomicAdd(&sums[0], 0.0f);   // coherent read
            float rs = unsafeAtomicAdd(&sums[1], 0.0f);
            out[0] = -ls / (float)BATCH;
            out[1] =  rs / (float)BATCH;
        }
    }
}

// ---------------------------------------------------------------------------
// Fallback path kernels (f32 COO atomic).
// ---------------------------------------------------------------------------
__global__ void init_f32_kernel(const float* __restrict__ uw, const float* __restrict__ iw,
                                const int* __restrict__ users, const int* __restrict__ pos,
                                const int* __restrict__ neg,
                                float* __restrict__ uacc, float* __restrict__ pacc,
                                float* __restrict__ nacc, float* __restrict__ reg_sum) {
    int tid = blockIdx.x * blockDim.x + threadIdx.x;
    int i = tid >> 4;
    int q = tid & 15;
    if (i >= BATCH) return;
    size_t o = (size_t)i * DIM + q * 4;
    float4 u = *(const float4*)(uw + (size_t)users[i] * DIM + q * 4);
    float4 p = *(const float4*)(iw + (size_t)pos[i]   * DIM + q * 4);
    float4 n = *(const float4*)(iw + (size_t)neg[i]   * DIM + q * 4);
    *(float4*)(uacc + o) = u;
    *(float4*)(pacc + o) = p;
    *(float4*)(nacc + o) = n;
    float ss = u.x*u.x + u.y*u.y + u.z*u.z + u.w*u.w
             + p.x*p.x + p.y*p.y + p.z*p.z + p.w*p.w
             + n.x*n.x + n.y*n.y + n.z*n.z + n.w*n.w;
    float bt = block_reduce_sum(ss);
    if (threadIdx.x == 0) unsafeAtomicAdd(reg_sum, bt);
}

__global__ void gather_add_kernel(const float* __restrict__ x,
                                  const int* __restrict__ users, const int* __restrict__ pos,
                                  const int* __restrict__ neg,
                                  float* __restrict__ uacc, float* __restrict__ pacc,
                                  float* __restrict__ nacc) {
    int tid = blockIdx.x * blockDim.x + threadIdx.x;
    int i = tid >> 4;
    int q = tid & 15;
    if (i >= BATCH) return;
    size_t o = (size_t)i * DIM + q * 4;
    float4 a, b;
    a = *(float4*)(uacc + o);
    b = *(const float4*)(x + (size_t)users[i] * DIM + q * 4);
    a.x += b.x; a.y += b.y; a.z += b.z; a.w += b.w;
    *(float4*)(uacc + o) = a;
    a = *(float4*)(pacc + o);
    b = *(const float4*)(x + (size_t)(N_USERS + pos[i]) * DIM + q * 4);
    a.x += b.x; a.y += b.y; a.z += b.z; a.w += b.w;
    *(float4*)(pacc + o) = a;
    a = *(float4*)(nacc + o);
    b = *(const float4*)(x + (size_t)(N_USERS + neg[i]) * DIM + q * 4);
    a.x += b.x; a.y += b.y; a.z += b.z; a.w += b.w;
    *(float4*)(nacc + o) = a;
}

__global__ void score_kernel(const float* __restrict__ uacc, const float* __restrict__ pacc,
                             const float* __restrict__ nacc, float* __restrict__ loss_sum) {
    int tid = blockIdx.x * blockDim.x + threadIdx.x;
    int i = tid >> 4;
    int q = tid & 15;
    float ps = 0.0f, ns = 0.0f;
    if (i < BATCH) {
        size_t o = (size_t)i * DIM + q * 4;
        float4 u = *(const float4*)(uacc + o);
        float4 p = *(const float4*)(pacc + o);
        float4 n = *(const float4*)(nacc + o);
        ps = u.x*p.x + u.y*p.y + u.z*p.z + u.w*p.w;
        ns = u.x*n.x + u.y*n.y + u.z*n.z + u.w*n.w;
    }
    for (int s = 8; s > 0; s >>= 1) {
        ps += __shfl_xor(ps, s, 16);
        ns += __shfl_xor(ns, s, 16);
    }
    float term = 0.0f;
    if (q == 0 && i < BATCH) {
        float d = (ps - ns) * (1.0f / 16.0f);
        float sig = 1.0f / (1.0f + expf(-d));
        term = logf(sig + 1e-8f);
    }
    float bt = block_reduce_sum(term);
    if (threadIdx.x == 0) unsafeAtomicAdd(loss_sum, bt);
}

__global__ void finalize_kernel(const float* __restrict__ sums, float* __restrict__ out) {
    if (threadIdx.x == 0 && blockIdx.x == 0) {
        out[0] = -sums[0] / (float)BATCH;
        out[1] =  sums[1] / (float)BATCH;
    }
}

static inline size_t align256(size_t x) { return (x + 255) & ~(size_t)255; }

extern "C" void kernel_launch(void* const* d_in, const int* in_sizes, int n_in,
                              void* d_out, int out_size, void* d_ws, size_t ws_size,
                              hipStream_t stream) {
    const float* uw   = (const float*)d_in[0];
    const float* iw   = (const float*)d_in[1];
    const float* vals = (const float*)d_in[2];
    const int*   rows = (const int*)d_in[3];
    const int*   cols = (const int*)d_in[4];
    const int*   users = (const int*)d_in[5];
    const int*   pos   = (const int*)d_in[6];
    const int*   neg   = (const int*)d_in[7];
    const int nnz = in_sizes[2];

    char* ws = (char*)d_ws;
    const size_t nodeBytes = (size_t)N_NODES * DIM * sizeof(float);   // 38.4 MB
    const size_t qBytes    = (size_t)N_NODES * DIM;                   // 9.6 MB (fp8)
    const size_t accBytes  = (size_t)BATCH * DIM * sizeof(float);

    size_t off = 0;
    char*  nodeReg = ws + off;            off += align256(2 * nodeBytes);   // 76.8 MB region
    float* uacc = (float*)(ws + off);     off += align256(accBytes);
    float* pacc = (float*)(ws + off);     off += align256(accBytes);
    float* nacc = (float*)(ws + off);     off += align256(accBytes);
    // --- contiguous zero region: sums | ctrl | bcursor | flags ---
    size_t zero_base = off;
    float* sums = (float*)(ws + off);     off += 256;   // [0]=loss, [1]=reg
    int*   ctrl = (int*)(ws + off);       off += 256;   // [0]=wl_cnt, [1]=ticket
    int*   bcursor= (int*)(ws + off);     off += align256((size_t)NB * sizeof(int));
    int*   flags  = (int*)(ws + off);     off += align256((size_t)N_NODES * sizeof(int));
    size_t zero_bytes = off - zero_base;
    // --- rest ---
    Pair*  perm = (Pair*)(ws + off);      off += align256((size_t)nnz * sizeof(Pair));
    int*   rowptr = (int*)(ws + off);     off += align256((size_t)(N_NODES + 1) * sizeof(int));
    int*   bbase  = (int*)(ws + off);     off += align256((size_t)(NB + 1) * sizeof(int));
    int*   wl     = (int*)(ws + off);     off += align256((size_t)(3 * BATCH) * sizeof(int));
    const bool fits_alias = (2 * align256(qBytes) + (size_t)NB * STRIDE * sizeof(Pair)) <= 2 * nodeBytes;
    const bool use_csr = (off <= ws_size) && fits_alias && (N_NODES < (1 << 18));

    unsigned char* xb0 = (unsigned char*)nodeReg;
    unsigned char* xb1 = (unsigned char*)(nodeReg + align256(qBytes));
    unsigned char* xb2 = (unsigned char*)(nodeReg + 2 * align256(qBytes));
    Pair*          bcv = (Pair*)(nodeReg + 2 * align256(qBytes));
    float* xA = (float*)nodeReg;
    float* xB = (float*)(nodeReg + nodeBytes);

    float* out = (float*)d_out;

    const int bthreads = BATCH * 16;
    const int bblocks  = bthreads / 256;          // 1024
    const int scb      = (nnz + TILE_E - 1) / TILE_E;   // 1172 scatter blocks

    if (use_csr) {
        (void)hipMemsetAsync(ws + zero_base, 0, zero_bytes, stream);
        // Fused scatter + convert + init (independent block ranges)
        build_kernel<<<scb + (int)CVB + INB, 512, 0, stream>>>(
            rows, cols, vals, bcursor, bcv, nnz, scb,
            uw, iw, xb0, users, pos, neg,
            uacc, pacc, nacc, sums + 1, flags, wl, ctrl);
        post_scan_kernel<<<1, 512, 0, stream>>>(bcursor, bbase, rowptr, nnz);
        bucket_sort_kernel<<<NB, 512, 0, stream>>>(bcv, bcursor, bbase, rowptr, perm);

        // Layer 1: xb0 -> xb1
        spmm_f8_kernel<<<SB, 256, 0, stream>>>(xb0, perm, rowptr, xb1);
        gather_add_f8_kernel<<<bblocks, 256, 0, stream>>>(xb1, users, pos, neg, uacc, pacc, nacc);
        // Layer 2: xb1 -> xb2 (bcv dead after sort)
        spmm_f8_kernel<<<SB, 256, 0, stream>>>(xb1, perm, rowptr, xb2);
        gather_add_f8_kernel<<<bblocks, 256, 0, stream>>>(xb2, users, pos, neg, uacc, pacc, nacc);
        // Layer 3: xb2 -> xb0, worklist rows only
        spmm_wl_f8_kernel<<<WLB, 256, 0, stream>>>(xb2, perm, rowptr, wl, ctrl, xb0);
        // Final gather + score + last-block finalize
        gather_score_kernel<<<bblocks, 256, 0, stream>>>(xb0, users, pos, neg,
                                                         uacc, pacc, nacc, sums, ctrl, out);
    } else {
        const long long sthreads = (long long)nnz * 16;
        const int sblocks = (int)((sthreads + 255) / 256);
        (void)hipMemsetAsync(sums, 0, 2 * sizeof(float), stream);
        init_f32_kernel<<<bblocks, 256, 0, stream>>>(uw, iw, users, pos, neg,
                                                     uacc, pacc, nacc, sums + 1);
        (void)hipMemsetAsync(xA, 0, nodeBytes, stream);
        spmm_atomic_kernel<<<sblocks, 256, 0, stream>>>(uw, iw, vals, rows, cols, xA, nnz);
        gather_add_kernel<<<bblocks, 256, 0, stream>>>(xA, users, pos, neg, uacc, pacc, nacc);
        (void)hipMemsetAsync(xB, 0, nodeBytes, stream);
        spmm_atomic_kernel<<<sblocks, 256, 0, stream>>>(xA, xA + (size_t)N_USERS * DIM, vals, rows, cols, xB, nnz);
        gather_add_kernel<<<bblocks, 256, 0, stream>>>(xB, users, pos, neg, uacc, pacc, nacc);
        (void)hipMemsetAsync(xA, 0, nodeBytes, stream);
        spmm_atomic_kernel<<<sblocks, 256, 0, stream>>>(xB, xB + (size_t)N_USERS * DIM, vals, rows, cols, xA, nnz);
        gather_add_kernel<<<bblocks, 256, 0, stream>>>(xA, users, pos, neg, uacc, pacc, nacc);
        score_kernel<<<bblocks, 256, 0, stream>>>(uacc, pacc, nacc, sums);
        finalize_kernel<<<1, 1, 0, stream>>>(sums, out);
    }
}

// Round 17
// 223.781 us; speedup vs baseline: 1.2143x; 1.0357x over previous
//
#include <hip/hip_runtime.h>

#define N_USERS 100000
#define N_ITEMS 50000
#define N_NODES (N_USERS + N_ITEMS)
#define DIM 64
#define BATCH 16384
#define RPB 512                          // rows per bucket
#define BSHIFT 9                         // log2(RPB)
#define NB ((N_NODES + RPB - 1) / RPB)   // 293 buckets
#define HP 296                           // padded hist stride (9.4 KB LDS total)
#define EPT 8                            // edges per thread in scatter (EPT=4 regressed: R12/R16)
#define TILE_E (512 * EPT)               // 4096 edges per scatter block
#define STRIDE 12288                     // bcv region stride (45-sigma headroom)
#define XSCALE 64.0f                     // fp8 storage scale
#define INV_XSCALE 0.015625f             // 1/64
#define SB ((N_NODES + 15) / 16)         // 9375 spmm blocks (16 rows/block)
#define WLB ((3 * BATCH) / 16)           // 3072 worklist spmm blocks
// fused build_kernel block partition (512 threads/block)
#define CVB (((size_t)N_NODES * DIM / 8 + 511) / 512)   // 2344 convert blocks
#define INB (BATCH * 16 / 512)                          // 512 init blocks

struct __align__(8) Pair { int c; float v; };
typedef float floatx2 __attribute__((ext_vector_type(2)));

// ---- fp8 helpers (e4m3, gfx940+ builtins) ---------------------------------
__device__ __forceinline__ unsigned pk8(float a, float b, float c, float d) {
    int w = __builtin_amdgcn_cvt_pk_fp8_f32(a, b, 0, false);
    w = __builtin_amdgcn_cvt_pk_fp8_f32(c, d, w, true);
    return (unsigned)w;
}

// acc(a0..a3) += v * fp8x4(x)   — 2 cvt + 4 fma
#define EDGE_F8D(V, X) { \
    floatx2 lo_ = __builtin_amdgcn_cvt_pk_f32_fp8((X), false); \
    floatx2 hi_ = __builtin_amdgcn_cvt_pk_f32_fp8((X), true); \
    a0 = fmaf((V), lo_.x, a0); a1 = fmaf((V), lo_.y, a1); \
    a2 = fmaf((V), hi_.x, a2); a3 = fmaf((V), hi_.y, a3); }

// ---------------------------------------------------------------------------
__device__ __forceinline__ float block_reduce_sum(float v) {
    for (int s = 32; s > 0; s >>= 1) v += __shfl_xor(v, s, 64);
    __shared__ float sm[8];
    int lane = threadIdx.x & 63;
    int wid  = threadIdx.x >> 6;
    if (lane == 0) sm[wid] = v;
    __syncthreads();
    float t = 0.0f;
    if (threadIdx.x == 0) {
        int nw = (blockDim.x + 63) >> 6;
        for (int w = 0; w < nw; ++w) t += sm[w];
    }
    return t;
}

// ---------------------------------------------------------------------------
// Fused build: blocks [0,scb) binned scatter (EPT=8); [scb,scb+CVB) f32->fp8
// convert; [scb+CVB, +INB) init (acc0 gather + reg_sum + worklist dedup).
// flags/bcursor/sums/ctrl pre-zeroed by one hipMemsetAsync.
// ---------------------------------------------------------------------------
__global__ void build_kernel(const int* __restrict__ rows, const int* __restrict__ cols,
                             const float* __restrict__ vals, int* __restrict__ bcursor,
                             Pair* __restrict__ bcv, int nnz, int scb,
                             const float* __restrict__ uw, const float* __restrict__ iw,
                             unsigned char* __restrict__ x8,
                             const int* __restrict__ users, const int* __restrict__ pos,
                             const int* __restrict__ neg,
                             float* __restrict__ uacc, float* __restrict__ pacc,
                             float* __restrict__ nacc, float* __restrict__ reg_sum,
                             int* __restrict__ flags, int* __restrict__ wl,
                             int* __restrict__ ctrl) {
    __shared__ int h[8][HP];
    int t = threadIdx.x;
    if ((int)blockIdx.x < scb) {
        // ---- binned scatter (EPT=8) ----
        int w = t >> 6;
        for (int i = t; i < 8 * HP; i += 512) ((int*)h)[i] = 0;
        __syncthreads();
        long long tile = (long long)blockIdx.x * TILE_E;
        int er[EPT], cr[EPT];
        float vr[EPT];
        #pragma unroll
        for (int j = 0; j < EPT; ++j) {
            long long e = tile + t + j * 512;
            if (e < nnz) {
                int r = rows[e];
                er[j] = r;
                cr[j] = cols[e];
                vr[j] = vals[e];
                atomicAdd(&h[w][r >> BSHIFT], 1);
            } else er[j] = -1;
        }
        __syncthreads();
        for (int b = t; b < NB; b += 512) {
            int cw[8], tot = 0;
            #pragma unroll
            for (int w2 = 0; w2 < 8; ++w2) { cw[w2] = h[w2][b]; tot += cw[w2]; }
            int base = tot ? (b * STRIDE + atomicAdd(&bcursor[b], tot)) : 0;
            #pragma unroll
            for (int w2 = 0; w2 < 8; ++w2) { h[w2][b] = base; base += cw[w2]; }
        }
        __syncthreads();
        #pragma unroll
        for (int j = 0; j < EPT; ++j) {
            if (er[j] >= 0) {
                int r = er[j];
                int dst = atomicAdd(&h[w][r >> BSHIFT], 1);
                Pair p;
                p.c = cr[j] | ((r & (RPB - 1)) << 18);
                p.v = vr[j];
                bcv[dst] = p;
            }
        }
    } else if (blockIdx.x < (unsigned)(scb + (int)CVB)) {
        // ---- convert [uw;iw] -> fp8 ----
        size_t tid = (size_t)(blockIdx.x - scb) * 512 + t;
        size_t base = tid * 8;
        if (base >= (size_t)N_NODES * DIM) return;
        const float* src = (base < (size_t)N_USERS * DIM) ? uw + base
                                                          : iw + (base - (size_t)N_USERS * DIM);
        float4 a = ((const float4*)src)[0];
        float4 b = ((const float4*)src)[1];
        uint2 o;
        o.x = pk8(XSCALE * a.x, XSCALE * a.y, XSCALE * a.z, XSCALE * a.w);
        o.y = pk8(XSCALE * b.x, XSCALE * b.y, XSCALE * b.z, XSCALE * b.w);
        *(uint2*)(x8 + base) = o;
    } else {
        // ---- init: acc0 gather + reg_sum + worklist dedup ----
        int tid = (int)(blockIdx.x - scb - (int)CVB) * 512 + t;
        if (tid < 3 * BATCH) {
            int r = (tid < BATCH) ? users[tid]
                  : (tid < 2 * BATCH) ? N_USERS + pos[tid - BATCH]
                  : N_USERS + neg[tid - 2 * BATCH];
            if (atomicExch(&flags[r], 1) == 0) wl[atomicAdd(&ctrl[0], 1)] = r;
        }
        int i = tid >> 4;
        int q = tid & 15;
        float ss = 0.0f;
        if (i < BATCH) {
            size_t o = (size_t)i * DIM + q * 4;
            float4 u = *(const float4*)(uw + (size_t)users[i] * DIM + q * 4);
            float4 p = *(const float4*)(iw + (size_t)pos[i]   * DIM + q * 4);
            float4 n = *(const float4*)(iw + (size_t)neg[i]   * DIM + q * 4);
            *(float4*)(uacc + o) = u;
            *(float4*)(pacc + o) = p;
            *(float4*)(nacc + o) = n;
            ss = u.x*u.x + u.y*u.y + u.z*u.z + u.w*u.w
               + p.x*p.x + p.y*p.y + p.z*p.z + p.w*p.w
               + n.x*n.x + n.y*n.y + n.z*n.z + n.w*n.w;
        }
        float bt = block_reduce_sum(ss);
        if (t == 0) unsafeAtomicAdd(reg_sum, bt);
    }
}

// ---------------------------------------------------------------------------
// Per-bucket counting sort in LDS -> final dense CSR perm + rowptr.
// Each block self-computes the bucket-count exclusive scan (no post_scan pass).
// ---------------------------------------------------------------------------
__global__ void bucket_sort_kernel(const Pair* __restrict__ bcv,
                                   const int* __restrict__ counts,
                                   int* __restrict__ rowptr, Pair* __restrict__ perm,
                                   int nnz) {
    __shared__ int rh8[8][RPB + 8];
    __shared__ int rh[RPB];
    __shared__ int sc[RPB];
    int blk = blockIdx.x;
    int t = threadIdx.x;        // 512 threads
    int w = t >> 6;
    size_t src = (size_t)blk * STRIDE;
    int cnt  = counts[blk];

    // --- phase 0: exclusive scan of bucket counts -> this bucket's base ---
    int cv = (t < NB) ? counts[t] : 0;
    sc[t] = cv;
    __syncthreads();
    for (int off = 1; off < 512; off <<= 1) {
        int tmp = (t >= off) ? sc[t - off] : 0;
        __syncthreads();
        sc[t] += tmp;
        __syncthreads();
    }
    int base = sc[blk] - cnt;   // exclusive prefix for this bucket
    if (blk == 0 && t == 0) rowptr[N_NODES] = nnz;
    __syncthreads();

    // --- phase 1: per-row histogram (8-way wave-replicated) ---
    for (int i = t; i < 8 * (RPB + 8); i += 512) ((int*)rh8)[i] = 0;
    __syncthreads();
    for (int i = t; i < cnt; i += 512)
        atomicAdd(&rh8[w][(unsigned)bcv[src + i].c >> 18], 1);
    __syncthreads();
    int v = 0;
    #pragma unroll
    for (int w2 = 0; w2 < 8; ++w2) v += rh8[w2][t];
    sc[t] = v;
    __syncthreads();
    for (int off = 1; off < 512; off <<= 1) {
        int tmp = (t >= off) ? sc[t - off] : 0;
        __syncthreads();
        sc[t] += tmp;
        __syncthreads();
    }
    int excl = sc[t] - v;
    int g = blk * RPB + t;
    if (g < N_NODES) rowptr[g] = base + excl;
    rh[t] = excl;
    __syncthreads();
    for (int i = t; i < cnt; i += 512) {
        Pair p = bcv[src + i];
        int r = (unsigned)p.c >> 18;
        int rk = atomicAdd(&rh[r], 1);
        p.c &= 0x3FFFF;
        perm[base + rk] = p;
    }
}

// ---------------------------------------------------------------------------
// SpMM per-row body (round-11 form): 16 lanes per row (lane owns one dword =
// 4 dims); 8-deep edge unroll with PLAIN loads (compiler schedules the
// vmcnt interleave better than a hand pipeline — measured R11 vs R13/R14).
// ---------------------------------------------------------------------------
__device__ __forceinline__ void spmm_row_f8(const unsigned char* __restrict__ x8,
                                            const Pair* __restrict__ pe,
                                            int e, int end, int q, int row,
                                            unsigned char* __restrict__ out8) {
    float a0 = 0.f, a1 = 0.f, a2 = 0.f, a3 = 0.f;
    for (; e + 7 < end; e += 8) {
        Pair p0 = pe[e],     p1 = pe[e + 1], p2 = pe[e + 2], p3 = pe[e + 3];
        Pair p4 = pe[e + 4], p5 = pe[e + 5], p6 = pe[e + 6], p7 = pe[e + 7];
        unsigned x0 = *(const unsigned*)(x8 + ((size_t)p0.c << 6) + q * 4);
        unsigned x1 = *(const unsigned*)(x8 + ((size_t)p1.c << 6) + q * 4);
        unsigned x2 = *(const unsigned*)(x8 + ((size_t)p2.c << 6) + q * 4);
        unsigned x3 = *(const unsigned*)(x8 + ((size_t)p3.c << 6) + q * 4);
        unsigned x4 = *(const unsigned*)(x8 + ((size_t)p4.c << 6) + q * 4);
        unsigned x5 = *(const unsigned*)(x8 + ((size_t)p5.c << 6) + q * 4);
        unsigned x6 = *(const unsigned*)(x8 + ((size_t)p6.c << 6) + q * 4);
        unsigned x7 = *(const unsigned*)(x8 + ((size_t)p7.c << 6) + q * 4);
        EDGE_F8D(p0.v, x0); EDGE_F8D(p1.v, x1);
        EDGE_F8D(p2.v, x2); EDGE_F8D(p3.v, x3);
        EDGE_F8D(p4.v, x4); EDGE_F8D(p5.v, x5);
        EDGE_F8D(p6.v, x6); EDGE_F8D(p7.v, x7);
    }
    for (; e + 1 < end; e += 2) {
        Pair p0 = pe[e], p1 = pe[e + 1];
        unsigned x0 = *(const unsigned*)(x8 + ((size_t)p0.c << 6) + q * 4);
        unsigned x1 = *(const unsigned*)(x8 + ((size_t)p1.c << 6) + q * 4);
        EDGE_F8D(p0.v, x0); EDGE_F8D(p1.v, x1);
    }
    if (e < end) {
        Pair p = pe[e];
        unsigned x = *(const unsigned*)(x8 + ((size_t)p.c << 6) + q * 4);
        EDGE_F8D(p.v, x);
    }
    *(unsigned*)(out8 + ((size_t)row << 6) + q * 4) = pk8(a0, a1, a2, a3);
}

// Full spmm (all rows).
__global__ void spmm_f8_kernel(const unsigned char* __restrict__ x8,
                               const Pair* __restrict__ pe,
                               const int* __restrict__ rowptr,
                               unsigned char* __restrict__ out8) {
    int row = blockIdx.x * 16 + (threadIdx.x >> 4);
    if (row >= N_NODES) return;
    spmm_row_f8(x8, pe, rowptr[row], rowptr[row + 1], threadIdx.x & 15, row, out8);
}

// Worklist spmm (layer 3: only rows consumed by the final gather).
__global__ void spmm_wl_f8_kernel(const unsigned char* __restrict__ x8,
                                  const Pair* __restrict__ pe,
                                  const int* __restrict__ rowptr,
                                  const int* __restrict__ wl,
                                  const int* __restrict__ ctrl,
                                  unsigned char* __restrict__ out8) {
    int idx = blockIdx.x * 16 + (threadIdx.x >> 4);
    if (idx >= ctrl[0]) return;
    int row = wl[idx];
    spmm_row_f8(x8, pe, rowptr[row], rowptr[row + 1], threadIdx.x & 15, row, out8);
}

// ---------------------------------------------------------------------------
// Legacy COO atomic SpMM (fallback).
// ---------------------------------------------------------------------------
__global__ void spmm_atomic_kernel(const float* __restrict__ xu, const float* __restrict__ xi,
                                   const float* __restrict__ vals, const int* __restrict__ rows,
                                   const int* __restrict__ cols,
                                   float* __restrict__ out, int nnz) {
    long long tid = (long long)blockIdx.x * blockDim.x + threadIdx.x;
    int e = (int)(tid >> 4);
    if (e >= nnz) return;
    int q = (int)(tid & 15);
    int r = rows[e];
    int c = cols[e];
    float v = vals[e];
    const float* src = (c < N_USERS) ? (xu + (size_t)c * DIM)
                                     : (xi + (size_t)(c - N_USERS) * DIM);
    float4 x = *(const float4*)(src + q * 4);
    float* dst = out + (size_t)r * DIM + q * 4;
    unsafeAtomicAdd(dst + 0, v * x.x);
    unsafeAtomicAdd(dst + 1, v * x.y);
    unsafeAtomicAdd(dst + 2, v * x.z);
    unsafeAtomicAdd(dst + 3, v * x.w);
}

// ---------------------------------------------------------------------------
// Gather-accumulate a layer's fp8 output at the batch rows only (unscale).
// ---------------------------------------------------------------------------
__global__ void gather_add_f8_kernel(const unsigned char* __restrict__ x8,
                                     const int* __restrict__ users, const int* __restrict__ pos,
                                     const int* __restrict__ neg,
                                     float* __restrict__ uacc, float* __restrict__ pacc,
                                     float* __restrict__ nacc) {
    int tid = blockIdx.x * blockDim.x + threadIdx.x;
    int i = tid >> 4;
    int q = tid & 15;
    if (i >= BATCH) return;
    size_t o = (size_t)i * DIM + q * 4;
    float4 a;
    unsigned u;
    floatx2 lo, hi;

    a = *(float4*)(uacc + o);
    u = *(const unsigned*)(x8 + ((size_t)users[i] << 6) + q * 4);
    lo = __builtin_amdgcn_cvt_pk_f32_fp8(u, false);
    hi = __builtin_amdgcn_cvt_pk_f32_fp8(u, true);
    a.x = fmaf(lo.x, INV_XSCALE, a.x); a.y = fmaf(lo.y, INV_XSCALE, a.y);
    a.z = fmaf(hi.x, INV_XSCALE, a.z); a.w = fmaf(hi.y, INV_XSCALE, a.w);
    *(float4*)(uacc + o) = a;

    a = *(float4*)(pacc + o);
    u = *(const unsigned*)(x8 + ((size_t)(N_USERS + pos[i]) << 6) + q * 4);
    lo = __builtin_amdgcn_cvt_pk_f32_fp8(u, false);
    hi = __builtin_amdgcn_cvt_pk_f32_fp8(u, true);
    a.x = fmaf(lo.x, INV_XSCALE, a.x); a.y = fmaf(lo.y, INV_XSCALE, a.y);
    a.z = fmaf(hi.x, INV_XSCALE, a.z); a.w = fmaf(hi.y, INV_XSCALE, a.w);
    *(float4*)(pacc + o) = a;

    a = *(float4*)(nacc + o);
    u = *(const unsigned*)(x8 + ((size_t)(N_USERS + neg[i]) << 6) + q * 4);
    lo = __builtin_amdgcn_cvt_pk_f32_fp8(u, false);
    hi = __builtin_amdgcn_cvt_pk_f32_fp8(u, true);
    a.x = fmaf(lo.x, INV_XSCALE, a.x); a.y = fmaf(lo.y, INV_XSCALE, a.y);
    a.z = fmaf(hi.x, INV_XSCALE, a.z); a.w = fmaf(hi.y, INV_XSCALE, a.w);
    *(float4*)(nacc + o) = a;
}

// ---------------------------------------------------------------------------
// Fused layer-3 gather + BPR score + last-block finalize.
// final = acc/4, so dot scales by 1/16.
// ---------------------------------------------------------------------------
__global__ void gather_score_kernel(const unsigned char* __restrict__ x8,
                                    const int* __restrict__ users, const int* __restrict__ pos,
                                    const int* __restrict__ neg,
                                    const float* __restrict__ uacc, const float* __restrict__ pacc,
                                    const float* __restrict__ nacc, float* __restrict__ sums,
                                    int* __restrict__ ctrl, float* __restrict__ out) {
    int tid = blockIdx.x * blockDim.x + threadIdx.x;
    int i = tid >> 4;
    int q = tid & 15;
    float ps = 0.0f, ns = 0.0f;
    if (i < BATCH) {
        size_t o = (size_t)i * DIM + q * 4;
        float4 u = *(const float4*)(uacc + o);
        float4 p = *(const float4*)(pacc + o);
        float4 n = *(const float4*)(nacc + o);
        unsigned t;
        floatx2 lo, hi;
        t = *(const unsigned*)(x8 + ((size_t)users[i] << 6) + q * 4);
        lo = __builtin_amdgcn_cvt_pk_f32_fp8(t, false);
        hi = __builtin_amdgcn_cvt_pk_f32_fp8(t, true);
        u.x = fmaf(lo.x, INV_XSCALE, u.x); u.y = fmaf(lo.y, INV_XSCALE, u.y);
        u.z = fmaf(hi.x, INV_XSCALE, u.z); u.w = fmaf(hi.y, INV_XSCALE, u.w);
        t = *(const unsigned*)(x8 + ((size_t)(N_USERS + pos[i]) << 6) + q * 4);
        lo = __builtin_amdgcn_cvt_pk_f32_fp8(t, false);
        hi = __builtin_amdgcn_cvt_pk_f32_fp8(t, true);
        p.x = fmaf(lo.x, INV_XSCALE, p.x); p.y = fmaf(lo.y, INV_XSCALE, p.y);
        p.z = fmaf(hi.x, INV_XSCALE, p.z); p.w = fmaf(hi.y, INV_XSCALE, p.w);
        t = *(const unsigned*)(x8 + ((size_t)(N_USERS + neg[i]) << 6) + q * 4);
        lo = __builtin_amdgcn_cvt_pk_f32_fp8(t, false);
        hi = __builtin_amdgcn_cvt_pk_f32_fp8(t, true);
        n.x = fmaf(lo.x, INV_XSCALE, n.x); n.y = fmaf(lo.y, INV_XSCALE, n.y);
        n.z = fmaf(hi.x, INV_XSCALE, n.z); n.w = fmaf(hi.y, INV_XSCALE, n.w);
        ps = u.x*p.x + u.y*p.y + u.z*p.z + u.w*p.w;
        ns = u.x*n.x + u.y*n.y + u.z*n.z + u.w*n.w;
    }
    for (int s = 8; s > 0; s >>= 1) {
        ps += __shfl_xor(ps, s, 16);
        ns += __shfl_xor(ns, s, 16);
    }
    float term = 0.0f;
    if (q == 0 && i < BATCH) {
        float d = (ps - ns) * (1.0f / 16.0f);
        float sig = 1.0f / (1.0f + expf(-d));
        term = logf(sig + 1e-8f);
    }
    float bt = block_reduce_sum(term);
    if (threadIdx.x == 0) {
        unsafeAtomicAdd(&sums[0], bt);
        __threadfence();
        int tk = atomicAdd(&ctrl[1], 1);
        if (tk == (int)gridDim.x - 1) {
            float ls = unsafeAtomicAdd(&sums[0], 0.0f);   // coherent read
            float rs = unsafeAtomicAdd(&sums[1], 0.0f);
            out[0] = -ls / (float)BATCH;
            out[1] =  rs / (float)BATCH;
        }
    }
}

// ---------------------------------------------------------------------------
// Fallback path kernels (f32 COO atomic).
// ---------------------------------------------------------------------------
__global__ void init_f32_kernel(const float* __restrict__ uw, const float* __restrict__ iw,
                                const int* __restrict__ users, const int* __restrict__ pos,
                                const int* __restrict__ neg,
                                float* __restrict__ uacc, float* __restrict__ pacc,
                                float* __restrict__ nacc, float* __restrict__ reg_sum) {
    int tid = blockIdx.x * blockDim.x + threadIdx.x;
    int i = tid >> 4;
    int q = tid & 15;
    if (i >= BATCH) return;
    size_t o = (size_t)i * DIM + q * 4;
    float4 u = *(const float4*)(uw + (size_t)users[i] * DIM + q * 4);
    float4 p = *(const float4*)(iw + (size_t)pos[i]   * DIM + q * 4);
    float4 n = *(const float4*)(iw + (size_t)neg[i]   * DIM + q * 4);
    *(float4*)(uacc + o) = u;
    *(float4*)(pacc + o) = p;
    *(float4*)(nacc + o) = n;
    float ss = u.x*u.x + u.y*u.y + u.z*u.z + u.w*u.w
             + p.x*p.x + p.y*p.y + p.z*p.z + p.w*p.w
             + n.x*n.x + n.y*n.y + n.z*n.z + n.w*n.w;
    float bt = block_reduce_sum(ss);
    if (threadIdx.x == 0) unsafeAtomicAdd(reg_sum, bt);
}

__global__ void gather_add_kernel(const float* __restrict__ x,
                                  const int* __restrict__ users, const int* __restrict__ pos,
                                  const int* __restrict__ neg,
                                  float* __restrict__ uacc, float* __restrict__ pacc,
                                  float* __restrict__ nacc) {
    int tid = blockIdx.x * blockDim.x + threadIdx.x;
    int i = tid >> 4;
    int q = tid & 15;
    if (i >= BATCH) return;
    size_t o = (size_t)i * DIM + q * 4;
    float4 a, b;
    a = *(float4*)(uacc + o);
    b = *(const float4*)(x + (size_t)users[i] * DIM + q * 4);
    a.x += b.x; a.y += b.y; a.z += b.z; a.w += b.w;
    *(float4*)(uacc + o) = a;
    a = *(float4*)(pacc + o);
    b = *(const float4*)(x + (size_t)(N_USERS + pos[i]) * DIM + q * 4);
    a.x += b.x; a.y += b.y; a.z += b.z; a.w += b.w;
    *(float4*)(pacc + o) = a;
    a = *(float4*)(nacc + o);
    b = *(const float4*)(x + (size_t)(N_USERS + neg[i]) * DIM + q * 4);
    a.x += b.x; a.y += b.y; a.z += b.z; a.w += b.w;
    *(float4*)(nacc + o) = a;
}

__global__ void score_kernel(const float* __restrict__ uacc, const float* __restrict__ pacc,
                             const float* __restrict__ nacc, float* __restrict__ loss_sum) {
    int tid = blockIdx.x * blockDim.x + threadIdx.x;
    int i = tid >> 4;
    int q = tid & 15;
    float ps = 0.0f, ns = 0.0f;
    if (i < BATCH) {
        size_t o = (size_t)i * DIM + q * 4;
        float4 u = *(const float4*)(uacc + o);
        float4 p = *(const float4*)(pacc + o);
        float4 n = *(const float4*)(nacc + o);
        ps = u.x*p.x + u.y*p.y + u.z*p.z + u.w*p.w;
        ns = u.x*n.x + u.y*n.y + u.z*n.z + u.w*n.w;
    }
    for (int s = 8; s > 0; s >>= 1) {
        ps += __shfl_xor(ps, s, 16);
        ns += __shfl_xor(ns, s, 16);
    }
    float term = 0.0f;
    if (q == 0 && i < BATCH) {
        float d = (ps - ns) * (1.0f / 16.0f);
        float sig = 1.0f / (1.0f + expf(-d));
        term = logf(sig + 1e-8f);
    }
    float bt = block_reduce_sum(term);
    if (threadIdx.x == 0) unsafeAtomicAdd(loss_sum, bt);
}

__global__ void finalize_kernel(const float* __restrict__ sums, float* __restrict__ out) {
    if (threadIdx.x == 0 && blockIdx.x == 0) {
        out[0] = -sums[0] / (float)BATCH;
        out[1] =  sums[1] / (float)BATCH;
    }
}

static inline size_t align256(size_t x) { return (x + 255) & ~(size_t)255; }

extern "C" void kernel_launch(void* const* d_in, const int* in_sizes, int n_in,
                              void* d_out, int out_size, void* d_ws, size_t ws_size,
                              hipStream_t stream) {
    const float* uw   = (const float*)d_in[0];
    const float* iw   = (const float*)d_in[1];
    const float* vals = (const float*)d_in[2];
    const int*   rows = (const int*)d_in[3];
    const int*   cols = (const int*)d_in[4];
    const int*   users = (const int*)d_in[5];
    const int*   pos   = (const int*)d_in[6];
    const int*   neg   = (const int*)d_in[7];
    const int nnz = in_sizes[2];

    char* ws = (char*)d_ws;
    const size_t nodeBytes = (size_t)N_NODES * DIM * sizeof(float);   // 38.4 MB
    const size_t qBytes    = (size_t)N_NODES * DIM;                   // 9.6 MB (fp8)
    const size_t accBytes  = (size_t)BATCH * DIM * sizeof(float);

    size_t off = 0;
    char*  nodeReg = ws + off;            off += align256(2 * nodeBytes);   // 76.8 MB region
    float* uacc = (float*)(ws + off);     off += align256(accBytes);
    float* pacc = (float*)(ws + off);     off += align256(accBytes);
    float* nacc = (float*)(ws + off);     off += align256(accBytes);
    // --- contiguous zero region: sums | ctrl | bcursor | flags ---
    size_t zero_base = off;
    float* sums = (float*)(ws + off);     off += 256;   // [0]=loss, [1]=reg
    int*   ctrl = (int*)(ws + off);       off += 256;   // [0]=wl_cnt, [1]=ticket
    int*   bcursor= (int*)(ws + off);     off += align256((size_t)NB * sizeof(int));
    int*   flags  = (int*)(ws + off);     off += align256((size_t)N_NODES * sizeof(int));
    size_t zero_bytes = off - zero_base;
    // --- rest ---
    Pair*  perm = (Pair*)(ws + off);      off += align256((size_t)nnz * sizeof(Pair));
    int*   rowptr = (int*)(ws + off);     off += align256((size_t)(N_NODES + 1) * sizeof(int));
    int*   wl     = (int*)(ws + off);     off += align256((size_t)(3 * BATCH) * sizeof(int));
    const bool fits_alias = (2 * align256(qBytes) + (size_t)NB * STRIDE * sizeof(Pair)) <= 2 * nodeBytes;
    const bool use_csr = (off <= ws_size) && fits_alias && (N_NODES < (1 << 18));

    unsigned char* xb0 = (unsigned char*)nodeReg;
    unsigned char* xb1 = (unsigned char*)(nodeReg + align256(qBytes));
    unsigned char* xb2 = (unsigned char*)(nodeReg + 2 * align256(qBytes));
    Pair*          bcv = (Pair*)(nodeReg + 2 * align256(qBytes));
    float* xA = (float*)nodeReg;
    float* xB = (float*)(nodeReg + nodeBytes);

    float* out = (float*)d_out;

    const int bthreads = BATCH * 16;
    const int bblocks  = bthreads / 256;          // 1024
    const int scb      = (nnz + TILE_E - 1) / TILE_E;   // 586 scatter blocks

    if (use_csr) {
        (void)hipMemsetAsync(ws + zero_base, 0, zero_bytes, stream);
        // Fused scatter + convert + init (independent block ranges)
        build_kernel<<<scb + (int)CVB + INB, 512, 0, stream>>>(
            rows, cols, vals, bcursor, bcv, nnz, scb,
            uw, iw, xb0, users, pos, neg,
            uacc, pacc, nacc, sums + 1, flags, wl, ctrl);
        bucket_sort_kernel<<<NB, 512, 0, stream>>>(bcv, bcursor, rowptr, perm, nnz);

        // Layer 1: xb0 -> xb1
        spmm_f8_kernel<<<SB, 256, 0, stream>>>(xb0, perm, rowptr, xb1);
        gather_add_f8_kernel<<<bblocks, 256, 0, stream>>>(xb1, users, pos, neg, uacc, pacc, nacc);
        // Layer 2: xb1 -> xb2 (bcv dead after sort)
        spmm_f8_kernel<<<SB, 256, 0, stream>>>(xb1, perm, rowptr, xb2);
        gather_add_f8_kernel<<<bblocks, 256, 0, stream>>>(xb2, users, pos, neg, uacc, pacc, nacc);
        // Layer 3: xb2 -> xb0, worklist rows only
        spmm_wl_f8_kernel<<<WLB, 256, 0, stream>>>(xb2, perm, rowptr, wl, ctrl, xb0);
        // Final gather + score + last-block finalize
        gather_score_kernel<<<bblocks, 256, 0, stream>>>(xb0, users, pos, neg,
                                                         uacc, pacc, nacc, sums, ctrl, out);
    } else {
        const long long sthreads = (long long)nnz * 16;
        const int sblocks = (int)((sthreads + 255) / 256);
        (void)hipMemsetAsync(sums, 0, 2 * sizeof(float), stream);
        init_f32_kernel<<<bblocks, 256, 0, stream>>>(uw, iw, users, pos, neg,
                                                     uacc, pacc, nacc, sums + 1);
        (void)hipMemsetAsync(xA, 0, nodeBytes, stream);
        spmm_atomic_kernel<<<sblocks, 256, 0, stream>>>(uw, iw, vals, rows, cols, xA, nnz);
        gather_add_kernel<<<bblocks, 256, 0, stream>>>(xA, users, pos, neg, uacc, pacc, nacc);
        (void)hipMemsetAsync(xB, 0, nodeBytes, stream);
        spmm_atomic_kernel<<<sblocks, 256, 0, stream>>>(xA, xA + (size_t)N_USERS * DIM, vals, rows, cols, xB, nnz);
        gather_add_kernel<<<bblocks, 256, 0, stream>>>(xB, users, pos, neg, uacc, pacc, nacc);
        (void)hipMemsetAsync(xA, 0, nodeBytes, stream);
        spmm_atomic_kernel<<<sblocks, 256, 0, stream>>>(xB, xB + (size_t)N_USERS * DIM, vals, rows, cols, xA, nnz);
        gather_add_kernel<<<bblocks, 256, 0, stream>>>(xA, users, pos, neg, uacc, pacc, nacc);
        score_kernel<<<bblocks, 256, 0, stream>>>(uacc, pacc, nacc, sums);
        finalize_kernel<<<1, 1, 0, stream>>>(sums, out);
    }
}

// Round 18
// 222.901 us; speedup vs baseline: 1.2191x; 1.0039x over previous
//
#include <hip/hip_runtime.h>

#define N_USERS 100000
#define N_ITEMS 50000
#define N_NODES (N_USERS + N_ITEMS)
#define DIM 64
#define BATCH 16384
#define RPB 512                          // rows per bucket
#define BSHIFT 9                         // log2(RPB)
#define NB ((N_NODES + RPB - 1) / RPB)   // 293 buckets
#define HP 296                           // padded hist stride (9.4 KB LDS total)
#define EPT 8                            // edges per thread in scatter (EPT=4 regressed: R12/R16)
#define TILE_E (512 * EPT)               // 4096 edges per scatter block
#define STRIDE 12288                     // bcv region stride (45-sigma headroom)
#define XSCALE 64.0f                     // fp8 storage scale
#define INV_XSCALE 0.015625f             // 1/64
#define SB ((N_NODES + 15) / 16)         // 9375 spmm blocks (16 rows/block)
#define WLB ((3 * BATCH) / 16)           // 3072 worklist spmm blocks
// fused build_kernel block partition (512 threads/block)
#define CVB (((size_t)N_NODES * DIM / 8 + 511) / 512)   // 2344 convert blocks
#define INB (BATCH * 16 / 512)                          // 512 init blocks

struct __align__(8) Pair { int c; float v; };
typedef float floatx2 __attribute__((ext_vector_type(2)));

// ---- fp8 helpers (e4m3, gfx940+ builtins) ---------------------------------
__device__ __forceinline__ unsigned pk8(float a, float b, float c, float d) {
    int w = __builtin_amdgcn_cvt_pk_fp8_f32(a, b, 0, false);
    w = __builtin_amdgcn_cvt_pk_fp8_f32(c, d, w, true);
    return (unsigned)w;
}

// acc(a0..a3) += v * fp8x4(x)   — 2 cvt + 4 fma
#define EDGE_F8D(V, X) { \
    floatx2 lo_ = __builtin_amdgcn_cvt_pk_f32_fp8((X), false); \
    floatx2 hi_ = __builtin_amdgcn_cvt_pk_f32_fp8((X), true); \
    a0 = fmaf((V), lo_.x, a0); a1 = fmaf((V), lo_.y, a1); \
    a2 = fmaf((V), hi_.x, a2); a3 = fmaf((V), hi_.y, a3); }

// ---------------------------------------------------------------------------
__device__ __forceinline__ float block_reduce_sum(float v) {
    for (int s = 32; s > 0; s >>= 1) v += __shfl_xor(v, s, 64);
    __shared__ float sm[8];
    int lane = threadIdx.x & 63;
    int wid  = threadIdx.x >> 6;
    if (lane == 0) sm[wid] = v;
    __syncthreads();
    float t = 0.0f;
    if (threadIdx.x == 0) {
        int nw = (blockDim.x + 63) >> 6;
        for (int w = 0; w < nw; ++w) t += sm[w];
    }
    return t;
}

// ---------------------------------------------------------------------------
// Fused build: blocks [0,scb) binned scatter (EPT=8); [scb,scb+CVB) f32->fp8
// convert; [scb+CVB, +INB) init (acc0 gather + reg_sum + worklist dedup).
// flags/bcursor/sums/ctrl pre-zeroed by one hipMemsetAsync.
// Scatter phase 3 uses the RANKS RETURNED BY PHASE 1's atomicAdd (no second
// LDS atomic): dst = per-wave sub-run base (phase 2) + phase-1 rank.
// ---------------------------------------------------------------------------
__global__ void build_kernel(const int* __restrict__ rows, const int* __restrict__ cols,
                             const float* __restrict__ vals, int* __restrict__ bcursor,
                             Pair* __restrict__ bcv, int nnz, int scb,
                             const float* __restrict__ uw, const float* __restrict__ iw,
                             unsigned char* __restrict__ x8,
                             const int* __restrict__ users, const int* __restrict__ pos,
                             const int* __restrict__ neg,
                             float* __restrict__ uacc, float* __restrict__ pacc,
                             float* __restrict__ nacc, float* __restrict__ reg_sum,
                             int* __restrict__ flags, int* __restrict__ wl,
                             int* __restrict__ ctrl) {
    __shared__ int h[8][HP];
    int t = threadIdx.x;
    if ((int)blockIdx.x < scb) {
        // ---- binned scatter (EPT=8) ----
        int w = t >> 6;
        for (int i = t; i < 8 * HP; i += 512) ((int*)h)[i] = 0;
        __syncthreads();
        long long tile = (long long)blockIdx.x * TILE_E;
        int er[EPT], cr[EPT], rk[EPT];
        float vr[EPT];
        #pragma unroll
        for (int j = 0; j < EPT; ++j) {
            long long e = tile + t + j * 512;
            if (e < nnz) {
                int r = rows[e];
                er[j] = r;
                cr[j] = cols[e];
                vr[j] = vals[e];
                rk[j] = atomicAdd(&h[w][r >> BSHIFT], 1);   // dense rank in (wave,bucket)
            } else er[j] = -1;
        }
        __syncthreads();
        for (int b = t; b < NB; b += 512) {
            int cw[8], tot = 0;
            #pragma unroll
            for (int w2 = 0; w2 < 8; ++w2) { cw[w2] = h[w2][b]; tot += cw[w2]; }
            int base = tot ? (b * STRIDE + atomicAdd(&bcursor[b], tot)) : 0;
            #pragma unroll
            for (int w2 = 0; w2 < 8; ++w2) { h[w2][b] = base; base += cw[w2]; }
        }
        __syncthreads();
        #pragma unroll
        for (int j = 0; j < EPT; ++j) {
            if (er[j] >= 0) {
                int r = er[j];
                int dst = h[w][r >> BSHIFT] + rk[j];        // LDS read, no atomic
                Pair p;
                p.c = cr[j] | ((r & (RPB - 1)) << 18);
                p.v = vr[j];
                bcv[dst] = p;
            }
        }
    } else if (blockIdx.x < (unsigned)(scb + (int)CVB)) {
        // ---- convert [uw;iw] -> fp8 ----
        size_t tid = (size_t)(blockIdx.x - scb) * 512 + t;
        size_t base = tid * 8;
        if (base >= (size_t)N_NODES * DIM) return;
        const float* src = (base < (size_t)N_USERS * DIM) ? uw + base
                                                          : iw + (base - (size_t)N_USERS * DIM);
        float4 a = ((const float4*)src)[0];
        float4 b = ((const float4*)src)[1];
        uint2 o;
        o.x = pk8(XSCALE * a.x, XSCALE * a.y, XSCALE * a.z, XSCALE * a.w);
        o.y = pk8(XSCALE * b.x, XSCALE * b.y, XSCALE * b.z, XSCALE * b.w);
        *(uint2*)(x8 + base) = o;
    } else {
        // ---- init: acc0 gather + reg_sum + worklist dedup ----
        int tid = (int)(blockIdx.x - scb - (int)CVB) * 512 + t;
        if (tid < 3 * BATCH) {
            int r = (tid < BATCH) ? users[tid]
                  : (tid < 2 * BATCH) ? N_USERS + pos[tid - BATCH]
                  : N_USERS + neg[tid - 2 * BATCH];
            if (atomicExch(&flags[r], 1) == 0) wl[atomicAdd(&ctrl[0], 1)] = r;
        }
        int i = tid >> 4;
        int q = tid & 15;
        float ss = 0.0f;
        if (i < BATCH) {
            size_t o = (size_t)i * DIM + q * 4;
            float4 u = *(const float4*)(uw + (size_t)users[i] * DIM + q * 4);
            float4 p = *(const float4*)(iw + (size_t)pos[i]   * DIM + q * 4);
            float4 n = *(const float4*)(iw + (size_t)neg[i]   * DIM + q * 4);
            *(float4*)(uacc + o) = u;
            *(float4*)(pacc + o) = p;
            *(float4*)(nacc + o) = n;
            ss = u.x*u.x + u.y*u.y + u.z*u.z + u.w*u.w
               + p.x*p.x + p.y*p.y + p.z*p.z + p.w*p.w
               + n.x*n.x + n.y*n.y + n.z*n.z + n.w*n.w;
        }
        float bt = block_reduce_sum(ss);
        if (t == 0) unsafeAtomicAdd(reg_sum, bt);
    }
}

// ---------------------------------------------------------------------------
// Per-bucket counting sort in LDS -> final dense CSR perm + rowptr.
// Each block self-computes the bucket-count exclusive scan (no post_scan pass).
// ---------------------------------------------------------------------------
__global__ void bucket_sort_kernel(const Pair* __restrict__ bcv,
                                   const int* __restrict__ counts,
                                   int* __restrict__ rowptr, Pair* __restrict__ perm,
                                   int nnz) {
    __shared__ int rh8[8][RPB + 8];
    __shared__ int rh[RPB];
    __shared__ int sc[RPB];
    int blk = blockIdx.x;
    int t = threadIdx.x;        // 512 threads
    int w = t >> 6;
    size_t src = (size_t)blk * STRIDE;
    int cnt  = counts[blk];

    // --- phase 0: exclusive scan of bucket counts -> this bucket's base ---
    int cv = (t < NB) ? counts[t] : 0;
    sc[t] = cv;
    __syncthreads();
    for (int off = 1; off < 512; off <<= 1) {
        int tmp = (t >= off) ? sc[t - off] : 0;
        __syncthreads();
        sc[t] += tmp;
        __syncthreads();
    }
    int base = sc[blk] - cnt;   // exclusive prefix for this bucket
    if (blk == 0 && t == 0) rowptr[N_NODES] = nnz;
    __syncthreads();

    // --- phase 1: per-row histogram (8-way wave-replicated) ---
    for (int i = t; i < 8 * (RPB + 8); i += 512) ((int*)rh8)[i] = 0;
    __syncthreads();
    for (int i = t; i < cnt; i += 512)
        atomicAdd(&rh8[w][(unsigned)bcv[src + i].c >> 18], 1);
    __syncthreads();
    int v = 0;
    #pragma unroll
    for (int w2 = 0; w2 < 8; ++w2) v += rh8[w2][t];
    sc[t] = v;
    __syncthreads();
    for (int off = 1; off < 512; off <<= 1) {
        int tmp = (t >= off) ? sc[t - off] : 0;
        __syncthreads();
        sc[t] += tmp;
        __syncthreads();
    }
    int excl = sc[t] - v;
    int g = blk * RPB + t;
    if (g < N_NODES) rowptr[g] = base + excl;
    rh[t] = excl;
    __syncthreads();
    for (int i = t; i < cnt; i += 512) {
        Pair p = bcv[src + i];
        int r = (unsigned)p.c >> 18;
        int rk = atomicAdd(&rh[r], 1);
        p.c &= 0x3FFFF;
        perm[base + rk] = p;
    }
}

// ---------------------------------------------------------------------------
// SpMM per-row body (round-11 form): 16 lanes per row (lane owns one dword =
// 4 dims); 8-deep edge unroll with PLAIN loads (compiler schedules the
// vmcnt interleave better than a hand pipeline — measured R11 vs R13/R14).
// ---------------------------------------------------------------------------
__device__ __forceinline__ void spmm_row_f8(const unsigned char* __restrict__ x8,
                                            const Pair* __restrict__ pe,
                                            int e, int end, int q, int row,
                                            unsigned char* __restrict__ out8) {
    float a0 = 0.f, a1 = 0.f, a2 = 0.f, a3 = 0.f;
    for (; e + 7 < end; e += 8) {
        Pair p0 = pe[e],     p1 = pe[e + 1], p2 = pe[e + 2], p3 = pe[e + 3];
        Pair p4 = pe[e + 4], p5 = pe[e + 5], p6 = pe[e + 6], p7 = pe[e + 7];
        unsigned x0 = *(const unsigned*)(x8 + ((size_t)p0.c << 6) + q * 4);
        unsigned x1 = *(const unsigned*)(x8 + ((size_t)p1.c << 6) + q * 4);
        unsigned x2 = *(const unsigned*)(x8 + ((size_t)p2.c << 6) + q * 4);
        unsigned x3 = *(const unsigned*)(x8 + ((size_t)p3.c << 6) + q * 4);
        unsigned x4 = *(const unsigned*)(x8 + ((size_t)p4.c << 6) + q * 4);
        unsigned x5 = *(const unsigned*)(x8 + ((size_t)p5.c << 6) + q * 4);
        unsigned x6 = *(const unsigned*)(x8 + ((size_t)p6.c << 6) + q * 4);
        unsigned x7 = *(const unsigned*)(x8 + ((size_t)p7.c << 6) + q * 4);
        EDGE_F8D(p0.v, x0); EDGE_F8D(p1.v, x1);
        EDGE_F8D(p2.v, x2); EDGE_F8D(p3.v, x3);
        EDGE_F8D(p4.v, x4); EDGE_F8D(p5.v, x5);
        EDGE_F8D(p6.v, x6); EDGE_F8D(p7.v, x7);
    }
    for (; e + 1 < end; e += 2) {
        Pair p0 = pe[e], p1 = pe[e + 1];
        unsigned x0 = *(const unsigned*)(x8 + ((size_t)p0.c << 6) + q * 4);
        unsigned x1 = *(const unsigned*)(x8 + ((size_t)p1.c << 6) + q * 4);
        EDGE_F8D(p0.v, x0); EDGE_F8D(p1.v, x1);
    }
    if (e < end) {
        Pair p = pe[e];
        unsigned x = *(const unsigned*)(x8 + ((size_t)p.c << 6) + q * 4);
        EDGE_F8D(p.v, x);
    }
    *(unsigned*)(out8 + ((size_t)row << 6) + q * 4) = pk8(a0, a1, a2, a3);
}

// Full spmm (all rows).
__global__ void spmm_f8_kernel(const unsigned char* __restrict__ x8,
                               const Pair* __restrict__ pe,
                               const int* __restrict__ rowptr,
                               unsigned char* __restrict__ out8) {
    int row = blockIdx.x * 16 + (threadIdx.x >> 4);
    if (row >= N_NODES) return;
    spmm_row_f8(x8, pe, rowptr[row], rowptr[row + 1], threadIdx.x & 15, row, out8);
}

// Worklist spmm (layer 3: only rows consumed by the final gather).
__global__ void spmm_wl_f8_kernel(const unsigned char* __restrict__ x8,
                                  const Pair* __restrict__ pe,
                                  const int* __restrict__ rowptr,
                                  const int* __restrict__ wl,
                                  const int* __restrict__ ctrl,
                                  unsigned char* __restrict__ out8) {
    int idx = blockIdx.x * 16 + (threadIdx.x >> 4);
    if (idx >= ctrl[0]) return;
    int row = wl[idx];
    spmm_row_f8(x8, pe, rowptr[row], rowptr[row + 1], threadIdx.x & 15, row, out8);
}

// ---------------------------------------------------------------------------
// Legacy COO atomic SpMM (fallback).
// ---------------------------------------------------------------------------
__global__ void spmm_atomic_kernel(const float* __restrict__ xu, const float* __restrict__ xi,
                                   const float* __restrict__ vals, const int* __restrict__ rows,
                                   const int* __restrict__ cols,
                                   float* __restrict__ out, int nnz) {
    long long tid = (long long)blockIdx.x * blockDim.x + threadIdx.x;
    int e = (int)(tid >> 4);
    if (e >= nnz) return;
    int q = (int)(tid & 15);
    int r = rows[e];
    int c = cols[e];
    float v = vals[e];
    const float* src = (c < N_USERS) ? (xu + (size_t)c * DIM)
                                     : (xi + (size_t)(c - N_USERS) * DIM);
    float4 x = *(const float4*)(src + q * 4);
    float* dst = out + (size_t)r * DIM + q * 4;
    unsafeAtomicAdd(dst + 0, v * x.x);
    unsafeAtomicAdd(dst + 1, v * x.y);
    unsafeAtomicAdd(dst + 2, v * x.z);
    unsafeAtomicAdd(dst + 3, v * x.w);
}

// ---------------------------------------------------------------------------
// Gather-accumulate a layer's fp8 output at the batch rows only (unscale).
// ---------------------------------------------------------------------------
__global__ void gather_add_f8_kernel(const unsigned char* __restrict__ x8,
                                     const int* __restrict__ users, const int* __restrict__ pos,
                                     const int* __restrict__ neg,
                                     float* __restrict__ uacc, float* __restrict__ pacc,
                                     float* __restrict__ nacc) {
    int tid = blockIdx.x * blockDim.x + threadIdx.x;
    int i = tid >> 4;
    int q = tid & 15;
    if (i >= BATCH) return;
    size_t o = (size_t)i * DIM + q * 4;
    float4 a;
    unsigned u;
    floatx2 lo, hi;

    a = *(float4*)(uacc + o);
    u = *(const unsigned*)(x8 + ((size_t)users[i] << 6) + q * 4);
    lo = __builtin_amdgcn_cvt_pk_f32_fp8(u, false);
    hi = __builtin_amdgcn_cvt_pk_f32_fp8(u, true);
    a.x = fmaf(lo.x, INV_XSCALE, a.x); a.y = fmaf(lo.y, INV_XSCALE, a.y);
    a.z = fmaf(hi.x, INV_XSCALE, a.z); a.w = fmaf(hi.y, INV_XSCALE, a.w);
    *(float4*)(uacc + o) = a;

    a = *(float4*)(pacc + o);
    u = *(const unsigned*)(x8 + ((size_t)(N_USERS + pos[i]) << 6) + q * 4);
    lo = __builtin_amdgcn_cvt_pk_f32_fp8(u, false);
    hi = __builtin_amdgcn_cvt_pk_f32_fp8(u, true);
    a.x = fmaf(lo.x, INV_XSCALE, a.x); a.y = fmaf(lo.y, INV_XSCALE, a.y);
    a.z = fmaf(hi.x, INV_XSCALE, a.z); a.w = fmaf(hi.y, INV_XSCALE, a.w);
    *(float4*)(pacc + o) = a;

    a = *(float4*)(nacc + o);
    u = *(const unsigned*)(x8 + ((size_t)(N_USERS + neg[i]) << 6) + q * 4);
    lo = __builtin_amdgcn_cvt_pk_f32_fp8(u, false);
    hi = __builtin_amdgcn_cvt_pk_f32_fp8(u, true);
    a.x = fmaf(lo.x, INV_XSCALE, a.x); a.y = fmaf(lo.y, INV_XSCALE, a.y);
    a.z = fmaf(hi.x, INV_XSCALE, a.z); a.w = fmaf(hi.y, INV_XSCALE, a.w);
    *(float4*)(nacc + o) = a;
}

// ---------------------------------------------------------------------------
// Fused layer-3 gather + BPR score + last-block finalize.
// final = acc/4, so dot scales by 1/16.
// ---------------------------------------------------------------------------
__global__ void gather_score_kernel(const unsigned char* __restrict__ x8,
                                    const int* __restrict__ users, const int* __restrict__ pos,
                                    const int* __restrict__ neg,
                                    const float* __restrict__ uacc, const float* __restrict__ pacc,
                                    const float* __restrict__ nacc, float* __restrict__ sums,
                                    int* __restrict__ ctrl, float* __restrict__ out) {
    int tid = blockIdx.x * blockDim.x + threadIdx.x;
    int i = tid >> 4;
    int q = tid & 15;
    float ps = 0.0f, ns = 0.0f;
    if (i < BATCH) {
        size_t o = (size_t)i * DIM + q * 4;
        float4 u = *(const float4*)(uacc + o);
        float4 p = *(const float4*)(pacc + o);
        float4 n = *(const float4*)(nacc + o);
        unsigned t;
        floatx2 lo, hi;
        t = *(const unsigned*)(x8 + ((size_t)users[i] << 6) + q * 4);
        lo = __builtin_amdgcn_cvt_pk_f32_fp8(t, false);
        hi = __builtin_amdgcn_cvt_pk_f32_fp8(t, true);
        u.x = fmaf(lo.x, INV_XSCALE, u.x); u.y = fmaf(lo.y, INV_XSCALE, u.y);
        u.z = fmaf(hi.x, INV_XSCALE, u.z); u.w = fmaf(hi.y, INV_XSCALE, u.w);
        t = *(const unsigned*)(x8 + ((size_t)(N_USERS + pos[i]) << 6) + q * 4);
        lo = __builtin_amdgcn_cvt_pk_f32_fp8(t, false);
        hi = __builtin_amdgcn_cvt_pk_f32_fp8(t, true);
        p.x = fmaf(lo.x, INV_XSCALE, p.x); p.y = fmaf(lo.y, INV_XSCALE, p.y);
        p.z = fmaf(hi.x, INV_XSCALE, p.z); p.w = fmaf(hi.y, INV_XSCALE, p.w);
        t = *(const unsigned*)(x8 + ((size_t)(N_USERS + neg[i]) << 6) + q * 4);
        lo = __builtin_amdgcn_cvt_pk_f32_fp8(t, false);
        hi = __builtin_amdgcn_cvt_pk_f32_fp8(t, true);
        n.x = fmaf(lo.x, INV_XSCALE, n.x); n.y = fmaf(lo.y, INV_XSCALE, n.y);
        n.z = fmaf(hi.x, INV_XSCALE, n.z); n.w = fmaf(hi.y, INV_XSCALE, n.w);
        ps = u.x*p.x + u.y*p.y + u.z*p.z + u.w*p.w;
        ns = u.x*n.x + u.y*n.y + u.z*n.z + u.w*n.w;
    }
    for (int s = 8; s > 0; s >>= 1) {
        ps += __shfl_xor(ps, s, 16);
        ns += __shfl_xor(ns, s, 16);
    }
    float term = 0.0f;
    if (q == 0 && i < BATCH) {
        float d = (ps - ns) * (1.0f / 16.0f);
        float sig = 1.0f / (1.0f + expf(-d));
        term = logf(sig + 1e-8f);
    }
    float bt = block_reduce_sum(term);
    if (threadIdx.x == 0) {
        unsafeAtomicAdd(&sums[0], bt);
        __threadfence();
        int tk = atomicAdd(&ctrl[1], 1);
        if (tk == (int)gridDim.x - 1) {
            float ls = unsafeAtomicAdd(&sums[0], 0.0f);   // coherent read
            float rs = unsafeAtomicAdd(&sums[1], 0.0f);
            out[0] = -ls / (float)BATCH;
            out[1] =  rs / (float)BATCH;
        }
    }
}

// ---------------------------------------------------------------------------
// Fallback path kernels (f32 COO atomic).
// ---------------------------------------------------------------------------
__global__ void init_f32_kernel(const float* __restrict__ uw, const float* __restrict__ iw,
                                const int* __restrict__ users, const int* __restrict__ pos,
                                const int* __restrict__ neg,
                                float* __restrict__ uacc, float* __restrict__ pacc,
                                float* __restrict__ nacc, float* __restrict__ reg_sum) {
    int tid = blockIdx.x * blockDim.x + threadIdx.x;
    int i = tid >> 4;
    int q = tid & 15;
    if (i >= BATCH) return;
    size_t o = (size_t)i * DIM + q * 4;
    float4 u = *(const float4*)(uw + (size_t)users[i] * DIM + q * 4);
    float4 p = *(const float4*)(iw + (size_t)pos[i]   * DIM + q * 4);
    float4 n = *(const float4*)(iw + (size_t)neg[i]   * DIM + q * 4);
    *(float4*)(uacc + o) = u;
    *(float4*)(pacc + o) = p;
    *(float4*)(nacc + o) = n;
    float ss = u.x*u.x + u.y*u.y + u.z*u.z + u.w*u.w
             + p.x*p.x + p.y*p.y + p.z*p.z + p.w*p.w
             + n.x*n.x + n.y*n.y + n.z*n.z + n.w*n.w;
    float bt = block_reduce_sum(ss);
    if (threadIdx.x == 0) unsafeAtomicAdd(reg_sum, bt);
}

__global__ void gather_add_kernel(const float* __restrict__ x,
                                  const int* __restrict__ users, const int* __restrict__ pos,
                                  const int* __restrict__ neg,
                                  float* __restrict__ uacc, float* __restrict__ pacc,
                                  float* __restrict__ nacc) {
    int tid = blockIdx.x * blockDim.x + threadIdx.x;
    int i = tid >> 4;
    int q = tid & 15;
    if (i >= BATCH) return;
    size_t o = (size_t)i * DIM + q * 4;
    float4 a, b;
    a = *(float4*)(uacc + o);
    b = *(const float4*)(x + (size_t)users[i] * DIM + q * 4);
    a.x += b.x; a.y += b.y; a.z += b.z; a.w += b.w;
    *(float4*)(uacc + o) = a;
    a = *(float4*)(pacc + o);
    b = *(const float4*)(x + (size_t)(N_USERS + pos[i]) * DIM + q * 4);
    a.x += b.x; a.y += b.y; a.z += b.z; a.w += b.w;
    *(float4*)(pacc + o) = a;
    a = *(float4*)(nacc + o);
    b = *(const float4*)(x + (size_t)(N_USERS + neg[i]) * DIM + q * 4);
    a.x += b.x; a.y += b.y; a.z += b.z; a.w += b.w;
    *(float4*)(nacc + o) = a;
}

__global__ void score_kernel(const float* __restrict__ uacc, const float* __restrict__ pacc,
                             const float* __restrict__ nacc, float* __restrict__ loss_sum) {
    int tid = blockIdx.x * blockDim.x + threadIdx.x;
    int i = tid >> 4;
    int q = tid & 15;
    float ps = 0.0f, ns = 0.0f;
    if (i < BATCH) {
        size_t o = (size_t)i * DIM + q * 4;
        float4 u = *(const float4*)(uacc + o);
        float4 p = *(const float4*)(pacc + o);
        float4 n = *(const float4*)(nacc + o);
        ps = u.x*p.x + u.y*p.y + u.z*p.z + u.w*p.w;
        ns = u.x*n.x + u.y*n.y + u.z*n.z + u.w*n.w;
    }
    for (int s = 8; s > 0; s >>= 1) {
        ps += __shfl_xor(ps, s, 16);
        ns += __shfl_xor(ns, s, 16);
    }
    float term = 0.0f;
    if (q == 0 && i < BATCH) {
        float d = (ps - ns) * (1.0f / 16.0f);
        float sig = 1.0f / (1.0f + expf(-d));
        term = logf(sig + 1e-8f);
    }
    float bt = block_reduce_sum(term);
    if (threadIdx.x == 0) unsafeAtomicAdd(loss_sum, bt);
}

__global__ void finalize_kernel(const float* __restrict__ sums, float* __restrict__ out) {
    if (threadIdx.x == 0 && blockIdx.x == 0) {
        out[0] = -sums[0] / (float)BATCH;
        out[1] =  sums[1] / (float)BATCH;
    }
}

static inline size_t align256(size_t x) { return (x + 255) & ~(size_t)255; }

extern "C" void kernel_launch(void* const* d_in, const int* in_sizes, int n_in,
                              void* d_out, int out_size, void* d_ws, size_t ws_size,
                              hipStream_t stream) {
    const float* uw   = (const float*)d_in[0];
    const float* iw   = (const float*)d_in[1];
    const float* vals = (const float*)d_in[2];
    const int*   rows = (const int*)d_in[3];
    const int*   cols = (const int*)d_in[4];
    const int*   users = (const int*)d_in[5];
    const int*   pos   = (const int*)d_in[6];
    const int*   neg   = (const int*)d_in[7];
    const int nnz = in_sizes[2];

    char* ws = (char*)d_ws;
    const size_t nodeBytes = (size_t)N_NODES * DIM * sizeof(float);   // 38.4 MB
    const size_t qBytes    = (size_t)N_NODES * DIM;                   // 9.6 MB (fp8)
    const size_t accBytes  = (size_t)BATCH * DIM * sizeof(float);

    size_t off = 0;
    char*  nodeReg = ws + off;            off += align256(2 * nodeBytes);   // 76.8 MB region
    float* uacc = (float*)(ws + off);     off += align256(accBytes);
    float* pacc = (float*)(ws + off);     off += align256(accBytes);
    float* nacc = (float*)(ws + off);     off += align256(accBytes);
    // --- contiguous zero region: sums | ctrl | bcursor | flags ---
    size_t zero_base = off;
    float* sums = (float*)(ws + off);     off += 256;   // [0]=loss, [1]=reg
    int*   ctrl = (int*)(ws + off);       off += 256;   // [0]=wl_cnt, [1]=ticket
    int*   bcursor= (int*)(ws + off);     off += align256((size_t)NB * sizeof(int));
    int*   flags  = (int*)(ws + off);     off += align256((size_t)N_NODES * sizeof(int));
    size_t zero_bytes = off - zero_base;
    // --- rest ---
    Pair*  perm = (Pair*)(ws + off);      off += align256((size_t)nnz * sizeof(Pair));
    int*   rowptr = (int*)(ws + off);     off += align256((size_t)(N_NODES + 1) * sizeof(int));
    int*   wl     = (int*)(ws + off);     off += align256((size_t)(3 * BATCH) * sizeof(int));
    const bool fits_alias = (2 * align256(qBytes) + (size_t)NB * STRIDE * sizeof(Pair)) <= 2 * nodeBytes;
    const bool use_csr = (off <= ws_size) && fits_alias && (N_NODES < (1 << 18));

    unsigned char* xb0 = (unsigned char*)nodeReg;
    unsigned char* xb1 = (unsigned char*)(nodeReg + align256(qBytes));
    unsigned char* xb2 = (unsigned char*)(nodeReg + 2 * align256(qBytes));
    Pair*          bcv = (Pair*)(nodeReg + 2 * align256(qBytes));
    float* xA = (float*)nodeReg;
    float* xB = (float*)(nodeReg + nodeBytes);

    float* out = (float*)d_out;

    const int bthreads = BATCH * 16;
    const int bblocks  = bthreads / 256;          // 1024
    const int scb      = (nnz + TILE_E - 1) / TILE_E;   // 586 scatter blocks

    if (use_csr) {
        (void)hipMemsetAsync(ws + zero_base, 0, zero_bytes, stream);
        // Fused scatter + convert + init (independent block ranges)
        build_kernel<<<scb + (int)CVB + INB, 512, 0, stream>>>(
            rows, cols, vals, bcursor, bcv, nnz, scb,
            uw, iw, xb0, users, pos, neg,
            uacc, pacc, nacc, sums + 1, flags, wl, ctrl);
        bucket_sort_kernel<<<NB, 512, 0, stream>>>(bcv, bcursor, rowptr, perm, nnz);

        // Layer 1: xb0 -> xb1
        spmm_f8_kernel<<<SB, 256, 0, stream>>>(xb0, perm, rowptr, xb1);
        gather_add_f8_kernel<<<bblocks, 256, 0, stream>>>(xb1, users, pos, neg, uacc, pacc, nacc);
        // Layer 2: xb1 -> xb2 (bcv dead after sort)
        spmm_f8_kernel<<<SB, 256, 0, stream>>>(xb1, perm, rowptr, xb2);
        gather_add_f8_kernel<<<bblocks, 256, 0, stream>>>(xb2, users, pos, neg, uacc, pacc, nacc);
        // Layer 3: xb2 -> xb0, worklist rows only
        spmm_wl_f8_kernel<<<WLB, 256, 0, stream>>>(xb2, perm, rowptr, wl, ctrl, xb0);
        // Final gather + score + last-block finalize
        gather_score_kernel<<<bblocks, 256, 0, stream>>>(xb0, users, pos, neg,
                                                         uacc, pacc, nacc, sums, ctrl, out);
    } else {
        const long long sthreads = (long long)nnz * 16;
        const int sblocks = (int)((sthreads + 255) / 256);
        (void)hipMemsetAsync(sums, 0, 2 * sizeof(float), stream);
        init_f32_kernel<<<bblocks, 256, 0, stream>>>(uw, iw, users, pos, neg,
                                                     uacc, pacc, nacc, sums + 1);
        (void)hipMemsetAsync(xA, 0, nodeBytes, stream);
        spmm_atomic_kernel<<<sblocks, 256, 0, stream>>>(uw, iw, vals, rows, cols, xA, nnz);
        gather_add_kernel<<<bblocks, 256, 0, stream>>>(xA, users, pos, neg, uacc, pacc, nacc);
        (void)hipMemsetAsync(xB, 0, nodeBytes, stream);
        spmm_atomic_kernel<<<sblocks, 256, 0, stream>>>(xA, xA + (size_t)N_USERS * DIM, vals, rows, cols, xB, nnz);
        gather_add_kernel<<<bblocks, 256, 0, stream>>>(xB, users, pos, neg, uacc, pacc, nacc);
        (void)hipMemsetAsync(xA, 0, nodeBytes, stream);
        spmm_atomic_kernel<<<sblocks, 256, 0, stream>>>(xB, xB + (size_t)N_USERS * DIM, vals, rows, cols, xA, nnz);
        gather_add_kernel<<<bblocks, 256, 0, stream>>>(xA, users, pos, neg, uacc, pacc, nacc);
        score_kernel<<<bblocks, 256, 0, stream>>>(uacc, pacc, nacc, sums);
        finalize_kernel<<<1, 1, 0, stream>>>(sums, out);
    }
}